// Round 4
// baseline (897.438 us; speedup 1.0000x reference)
//
#include <hip/hip_runtime.h>
#include <hip/hip_bf16.h>

typedef unsigned short u16;
typedef __attribute__((ext_vector_type(4))) float f32x4;
typedef __attribute__((ext_vector_type(8))) _Float16 f16x8;
typedef __attribute__((ext_vector_type(4))) _Float16 f16x4;

// dims
#define NB 2
#define TT 4096
#define HID 1024
#define NHEAD 16
#define DH 64
#define NHT (NB * NHEAD)          // 32
#define QKV_ELEMS (NHT * TT * DH) // 8388608 per tensor
#define LO_SCALE 2048.0f          // 2^11
#define LO_INV   4.8828125e-4f    // 2^-11

// ---------------------------------------------------------------------------
// Kernel A: Q and V projection (fp32 in, fp16 MFMA, fp32/fp16 out).
// z=0: Q -> d_out (fp32, final [n,t,h,d] layout, reused as q storage)
// z=1: V -> ws (fp16, [nh,t,d])
// 128x128 tile, BK=32, 4 waves, MFMA f32_16x16x32_f16.
// ---------------------------------------------------------------------------
__global__ __launch_bounds__(256) void qv_gemm(
    const float* __restrict__ H,
    const float* __restrict__ Wq, const float* __restrict__ Wv,
    const float* __restrict__ bq, const float* __restrict__ bv,
    float* __restrict__ qout, u16* __restrict__ vout)
{
    const int z = blockIdx.z;
    const float* W    = (z == 0) ? Wq : Wv;
    const float* bias = (z == 0) ? bq : bv;

    __shared__ __align__(16) u16 Ah[128 * 32];
    __shared__ __align__(16) u16 Bh[128 * 32];

    const int tid  = threadIdx.x;
    const int lane = tid & 63;
    const int wid  = tid >> 6;
    const int wm = (wid >> 1) * 64;
    const int wn = (wid & 1) * 64;
    const int bm = blockIdx.x * 128;
    const int bn = blockIdx.y * 128;
    const int l15 = lane & 15, l4 = lane >> 4;

    f32x4 acc[4][4] = {};

    for (int k0 = 0; k0 < 1024; k0 += 32) {
#pragma unroll
        for (int it = 0; it < 4; it++) {
            int c = it * 256 + tid;          // 1024 float4-chunks per tile
            int row = c >> 3;                // 8 chunks per 32-float row
            int col = (c & 7) * 4;
            f32x4 a = *(const f32x4*)&H[(size_t)(bm + row) * 1024 + k0 + col];
            f32x4 b = *(const f32x4*)&W[(size_t)(bn + row) * 1024 + k0 + col];
            f16x4 ah, bh;
#pragma unroll
            for (int u = 0; u < 4; u++) { ah[u] = (_Float16)a[u]; bh[u] = (_Float16)b[u]; }
            *(f16x4*)&Ah[row * 32 + col] = ah;
            *(f16x4*)&Bh[row * 32 + col] = bh;
        }
        __syncthreads();

        f16x8 aF[4], bF[4];
#pragma unroll
        for (int i = 0; i < 4; i++) {
            aF[i] = *(const f16x8*)&Ah[(wm + i * 16 + l15) * 32 + l4 * 8];
            bF[i] = *(const f16x8*)&Bh[(wn + i * 16 + l15) * 32 + l4 * 8];
        }
#pragma unroll
        for (int i = 0; i < 4; i++)
#pragma unroll
            for (int j = 0; j < 4; j++)
                acc[i][j] = __builtin_amdgcn_mfma_f32_16x16x32_f16(aF[i], bF[j], acc[i][j], 0, 0, 0);
        __syncthreads();
    }

    float bvj[4];
#pragma unroll
    for (int j = 0; j < 4; j++) bvj[j] = bias[bn + wn + j * 16 + l15];

    // epilogue: C/D layout col = lane&15, row = (lane>>4)*4 + reg
#pragma unroll
    for (int i = 0; i < 4; i++) {
#pragma unroll
        for (int j = 0; j < 4; j++) {
            int col = bn + wn + j * 16 + l15;   // h*64 + d
            int hh = col >> 6, dd = col & 63;
#pragma unroll
            for (int r = 0; r < 4; r++) {
                int m = bm + wm + i * 16 + l4 * 4 + r;   // n*T + t
                float v = acc[i][j][r] + bvj[j];
                if (z == 0) {
                    qout[(size_t)m * HID + col] = v;     // q in out layout
                } else {
                    int nbat = m >> 12, t = m & 4095;
                    _Float16 hv = (_Float16)v;
                    vout[(((size_t)(nbat * NHEAD + hh)) * TT + t) * DH + dd] =
                        *(u16*)&hv;
                }
            }
        }
    }
}

// ---------------------------------------------------------------------------
// Kernel B: K projection with 2-term fp16 split (hi + 2^11*lo), 3 MFMAs.
// Near-fp32 accuracy so the norm-based top-k ordering matches the np ref.
// Writes K (fp16) + fp32 selection norms |k + bk + bq|^2.
// ---------------------------------------------------------------------------
__global__ __launch_bounds__(256) void k_gemm(
    const float* __restrict__ H, const float* __restrict__ Wk,
    const float* __restrict__ bk, const float* __restrict__ bq,
    u16* __restrict__ kout, float* __restrict__ norms)
{
    __shared__ __align__(16) u16 Ah[128 * 32];
    __shared__ __align__(16) u16 Al[128 * 32];
    __shared__ __align__(16) u16 Bh[128 * 32];
    __shared__ __align__(16) u16 Bl[128 * 32];

    const int tid  = threadIdx.x;
    const int lane = tid & 63;
    const int wid  = tid >> 6;
    const int wm = (wid >> 1) * 64;
    const int wn = (wid & 1) * 64;
    const int bm = blockIdx.x * 128;
    const int bn = blockIdx.y * 128;
    const int l15 = lane & 15, l4 = lane >> 4;

    f32x4 accM[4][4] = {};   // hi*hi
    f32x4 accC[4][4] = {};   // hi*(2^11 lo) + (2^11 lo)*hi

    for (int k0 = 0; k0 < 1024; k0 += 32) {
#pragma unroll
        for (int it = 0; it < 4; it++) {
            int c = it * 256 + tid;
            int row = c >> 3;
            int col = (c & 7) * 4;
            f32x4 a = *(const f32x4*)&H[(size_t)(bm + row) * 1024 + k0 + col];
            f32x4 b = *(const f32x4*)&Wk[(size_t)(bn + row) * 1024 + k0 + col];
            f16x4 ah, al, bh, bl;
#pragma unroll
            for (int u = 0; u < 4; u++) {
                _Float16 h = (_Float16)a[u];
                ah[u] = h; al[u] = (_Float16)((a[u] - (float)h) * LO_SCALE);
                _Float16 g = (_Float16)b[u];
                bh[u] = g; bl[u] = (_Float16)((b[u] - (float)g) * LO_SCALE);
            }
            *(f16x4*)&Ah[row * 32 + col] = ah;
            *(f16x4*)&Al[row * 32 + col] = al;
            *(f16x4*)&Bh[row * 32 + col] = bh;
            *(f16x4*)&Bl[row * 32 + col] = bl;
        }
        __syncthreads();

        f16x8 aH[4], aL[4], bH[4], bL[4];
#pragma unroll
        for (int i = 0; i < 4; i++) {
            int ao = (wm + i * 16 + l15) * 32 + l4 * 8;
            int bo = (wn + i * 16 + l15) * 32 + l4 * 8;
            aH[i] = *(const f16x8*)&Ah[ao];
            aL[i] = *(const f16x8*)&Al[ao];
            bH[i] = *(const f16x8*)&Bh[bo];
            bL[i] = *(const f16x8*)&Bl[bo];
        }
#pragma unroll
        for (int i = 0; i < 4; i++)
#pragma unroll
            for (int j = 0; j < 4; j++) {
                accM[i][j] = __builtin_amdgcn_mfma_f32_16x16x32_f16(aH[i], bH[j], accM[i][j], 0, 0, 0);
                accC[i][j] = __builtin_amdgcn_mfma_f32_16x16x32_f16(aH[i], bL[j], accC[i][j], 0, 0, 0);
                accC[i][j] = __builtin_amdgcn_mfma_f32_16x16x32_f16(aL[i], bH[j], accC[i][j], 0, 0, 0);
            }
        __syncthreads();
    }

    float bkj[4], bqj[4];
#pragma unroll
    for (int j = 0; j < 4; j++) {
        bkj[j] = bk[bn + wn + j * 16 + l15];
        bqj[j] = bq[bn + wn + j * 16 + l15];
    }

#pragma unroll
    for (int i = 0; i < 4; i++) {
#pragma unroll
        for (int r = 0; r < 4; r++) {
            int m = bm + wm + i * 16 + l4 * 4 + r;   // n*T + t
            int nbat = m >> 12, t = m & 4095;
            float sq = 0.f;
#pragma unroll
            for (int j = 0; j < 4; j++) {
                int col = bn + wn + j * 16 + l15;
                int hh = col >> 6, dd = col & 63;
                float kv = accM[i][j][r] + accC[i][j][r] * LO_INV + bkj[j];
                _Float16 hv = (_Float16)kv;
                kout[(((size_t)(nbat * NHEAD + hh)) * TT + t) * DH + dd] = *(u16*)&hv;
                float x = kv + bqj[j];
                sq = fmaf(x, x, sq);
            }
            // reduce over the 16 lanes (l15) holding this row's 64 cols
            sq += __shfl_xor(sq, 1);
            sq += __shfl_xor(sq, 2);
            sq += __shfl_xor(sq, 4);
            sq += __shfl_xor(sq, 8);
            if (l15 == 0) {
                int hh = (bn + wn) >> 6;
                norms[((size_t)(nbat * NHEAD + hh)) * TT + t] = sq;
            }
        }
    }
}

// ---------------------------------------------------------------------------
// Kernel C: norm-based top-k per 64-token chunk (stable rank by (norm, idx)).
// NaN-guarded: index arrays are always a full permutation.
// ---------------------------------------------------------------------------
__global__ __launch_bounds__(64) void select_topk(
    const float* __restrict__ norms_in, const float* __restrict__ mask,
    int* __restrict__ gidx, int* __restrict__ lidx)
{
    const int bid = blockIdx.x;          // nh*64 + c
    const int nh = bid >> 6, c = bid & 63;
    const int n = nh >> 4;
    const int tid = threadIdx.x;
    const int tok = c * 64 + tid;

    float nrm = norms_in[(size_t)nh * TT + tok];
    if (nrm != nrm) nrm = 0.f;                       // NaN guard
    if (mask[(size_t)n * TT + tok] != 0.f) nrm = 0.f;

    __shared__ float norms[64];
    __shared__ int flags[64];
    norms[tid] = nrm;
    __syncthreads();

    int rank = 0;
    for (int j = 0; j < 64; j++) {
        float nj = norms[j];
        rank += (nj < nrm || (nj == nrm && j < tid)) ? 1 : 0;
    }
    int istop = (rank >= 48) ? 1 : 0;
    flags[tid] = istop;
    __syncthreads();

    int pos = 0;
    for (int j = 0; j < tid; j++) pos += istop ? flags[j] : (1 - flags[j]);
    if (istop) gidx[(size_t)nh * 1024 + c * 16 + pos] = tok;
    else       lidx[(size_t)nh * 3072 + c * 48 + pos] = tok;
}

// ---------------------------------------------------------------------------
// Kernel D: BOS token — full UNSCALED attention over all keys; writes t=0.
// ---------------------------------------------------------------------------
__global__ __launch_bounds__(64) void bos_kernel(
    const u16* __restrict__ K, const u16* __restrict__ V,
    const float* __restrict__ mask, float* __restrict__ out)
{
    const int nh = blockIdx.x;
    const int n = nh >> 4, h = nh & 15;
    const int tid = threadIdx.x;
    const size_t base = (size_t)nh * TT * DH;

    float q[64];
    {
        const float* qr = out + ((size_t)n * TT) * HID + h * 64;  // q row t=0
#pragma unroll
        for (int i = 0; i < 16; i++) {
            f32x4 v = *(const f32x4*)&qr[i * 4];
#pragma unroll
            for (int u = 0; u < 4; u++) q[i * 4 + u] = v[u];
        }
    }

    float m_ = -1e30f, l_ = 0.f, acc[64];
#pragma unroll
    for (int d = 0; d < 64; d++) acc[d] = 0.f;

    for (int kk = tid; kk < TT; kk += 64) {
        const u16* kr = K + base + (size_t)kk * DH;
        const u16* vr = V + base + (size_t)kk * DH;
        float s = 0.f;
#pragma unroll
        for (int i = 0; i < 8; i++) {
            f16x8 kv = *(const f16x8*)&kr[i * 8];
#pragma unroll
            for (int u = 0; u < 8; u++) s = fmaf(q[i * 8 + u], (float)kv[u], s);
        }
        s += mask[(size_t)n * TT + kk];   // unscaled
        float mn = fmaxf(m_, s);
        float sc = __expf(m_ - mn);
        float p  = __expf(s - mn);
        l_ = l_ * sc + p;
#pragma unroll
        for (int i = 0; i < 8; i++) {
            f16x8 vv = *(const f16x8*)&vr[i * 8];
#pragma unroll
            for (int u = 0; u < 8; u++)
                acc[i * 8 + u] = fmaf(acc[i * 8 + u], sc, p * (float)vv[u]);
        }
        m_ = mn;
    }

    __shared__ float ms[64], ls[64], accs[64][65];
    ms[tid] = m_; ls[tid] = l_;
#pragma unroll
    for (int d = 0; d < 64; d++) accs[tid][d] = acc[d];
    __syncthreads();

    float M = -1e30f;
    for (int j = 0; j < 64; j++) M = fmaxf(M, ms[j]);
    float L = 0.f;
    for (int j = 0; j < 64; j++) L += ls[j] * __expf(ms[j] - M);
    float sum = 0.f;
    for (int j = 0; j < 64; j++) sum = fmaf(accs[j][tid], __expf(ms[j] - M), sum);
    out[((size_t)n * TT) * HID + h * 64 + tid] = sum / L;
}

// ---------------------------------------------------------------------------
// Kernel E: fused selected-global + local attention + lse merge.
// One wave per (n,h,64-query chunk); one query/thread; online softmax.
// Reads q (fp32) from d_out rows, overwrites same rows. Skips t=0 store.
// ---------------------------------------------------------------------------
__global__ __launch_bounds__(64) void attn_kernel(
    const u16* __restrict__ K, const u16* __restrict__ V,
    const int* __restrict__ gidx, const int* __restrict__ lidx,
    const float* __restrict__ mask, float* __restrict__ out)
{
    const int bid = blockIdx.x;
    const int nh = bid >> 6, c = bid & 63;
    const int n = nh >> 4, h = nh & 15;
    const int tid = threadIdx.x;
    const int t = c * 64 + tid;
    const size_t kvbase = (size_t)nh * TT * DH;
    const size_t ob = ((size_t)n * TT + t) * HID + h * 64;   // q row == out row

    float q[64];
    {
        const float* qr = out + ob;
#pragma unroll
        for (int i = 0; i < 16; i++) {
            f32x4 v = *(const f32x4*)&qr[i * 4];
#pragma unroll
            for (int u = 0; u < 4; u++) q[i * 4 + u] = v[u];
        }
    }

    __shared__ float ctxg[64][65];

    float m_ = -1e30f, l_ = 0.f;
    float acc[64];
#pragma unroll
    for (int d = 0; d < 64; d++) acc[d] = 0.f;

    auto step = [&](int key, float madd) {
        const u16* kr = K + kvbase + (size_t)key * DH;
        const u16* vr = V + kvbase + (size_t)key * DH;
        float s = 0.f;
#pragma unroll
        for (int i = 0; i < 8; i++) {
            f16x8 kv = *(const f16x8*)&kr[i * 8];
#pragma unroll
            for (int u = 0; u < 8; u++) s = fmaf(q[i * 8 + u], (float)kv[u], s);
        }
        s = s * 0.125f + madd;
        float mn = fmaxf(m_, s);
        float sc = __expf(m_ - mn);
        float p  = __expf(s - mn);
        l_ = l_ * sc + p;
#pragma unroll
        for (int i = 0; i < 8; i++) {
            f16x8 vv = *(const f16x8*)&vr[i * 8];
#pragma unroll
            for (int u = 0; u < 8; u++)
                acc[i * 8 + u] = fmaf(acc[i * 8 + u], sc, p * (float)vv[u]);
        }
        m_ = mn;
    };

    // ---- global (selected) pass: window of 3 x 16 keys
    for (int w = -1; w <= 1; w++) {
        int blk = c + w;
        if (blk < 0 || blk >= 64) continue;
        for (int j = 0; j < 16; j++) {
            int key = gidx[(size_t)nh * 1024 + blk * 16 + j];
            key = __builtin_amdgcn_readfirstlane(key) & 4095;   // never OOB
            step(key, mask[(size_t)n * TT + key]);
        }
    }
    float lse_g = m_ + __logf(l_);
    {
        float linv = 1.f / l_;
#pragma unroll
        for (int d = 0; d < 64; d++) ctxg[tid][d] = acc[d] * linv;
    }

    // ---- local pass: global key (token 0, mask 0) + window of 3 x 96 keys
    m_ = -1e30f; l_ = 0.f;
#pragma unroll
    for (int d = 0; d < 64; d++) acc[d] = 0.f;

    step(0, 0.f);   // appended gk/gv with zero mask
    int bl = c >> 1;
    for (int w = -1; w <= 1; w++) {
        int blk = bl + w;
        if (blk < 0 || blk >= 32) continue;
        for (int j = 0; j < 96; j++) {
            int key = lidx[(size_t)nh * 3072 + blk * 96 + j];
            key = __builtin_amdgcn_readfirstlane(key) & 4095;   // never OOB
            step(key, mask[(size_t)n * TT + key]);
        }
    }
    float lse_l = m_ + __logf(l_);

    float p = 1.f / (1.f + __expf(lse_g - lse_l));
    float linv_l = 1.f / l_;
    if (t != 0) {   // t=0 row holds the bos result — keep it
#pragma unroll
        for (int d = 0; d < 64; d++) {
            float cl = acc[d] * linv_l;
            float cg = ctxg[tid][d];
            out[ob + d] = cg + p * (cl - cg);
        }
    }
}

// ---------------------------------------------------------------------------
__global__ void ws_sentinel(float* out, int n, float val) {
    int i = blockIdx.x * 256 + threadIdx.x;
    if (i < n) out[i] = val;
}

// ---------------------------------------------------------------------------
extern "C" void kernel_launch(void* const* d_in, const int* in_sizes, int n_in,
                              void* d_out, int out_size, void* d_ws, size_t ws_size,
                              hipStream_t stream) {
    // identify inputs by element count (robust to reordering):
    // H=8388608, mask=8192, W*=1048576 (order q,k,v), b*=1024 (order q,k,v)
    int iH = 0, iM = 1, iW[3] = {2, 4, 6}, ib[3] = {3, 5, 7};
    {
        int nw = 0, nb2 = 0, seenH = 0, seenM = 0;
        for (int i = 0; i < n_in; i++) {
            int s = in_sizes[i];
            if (s == 8388608 && !seenH) { iH = i; seenH = 1; }
            else if (s == 8192 && !seenM) { iM = i; seenM = 1; }
            else if (s == 1048576 && nw < 3) iW[nw++] = i;
            else if (s == 1024 && nb2 < 3) ib[nb2++] = i;
        }
    }
    const float* H    = (const float*)d_in[iH];
    const float* mask = (const float*)d_in[iM];
    const float* Wq = (const float*)d_in[iW[0]];
    const float* Wk = (const float*)d_in[iW[1]];
    const float* Wv = (const float*)d_in[iW[2]];
    const float* bq = (const float*)d_in[ib[0]];
    const float* bk = (const float*)d_in[ib[1]];
    const float* bv = (const float*)d_in[ib[2]];
    float* out = (float*)d_out;

    // ws: K,V fp16 (32 MiB) + norms fp32 (512 KiB) + indices (512 KiB)
    const size_t WS_NEED = (size_t)2 * QKV_ELEMS * 2 + (size_t)NHT * TT * 4
                         + (size_t)NHT * 1024 * 4 + (size_t)NHT * 3072 * 4;
    if (ws_size < WS_NEED) {
        float val = (float)(ws_size >> 20);
        ws_sentinel<<<(out_size + 255) / 256, 256, 0, stream>>>(out, out_size, val);
        return;
    }

    u16* Kb = (u16*)d_ws;                             // [32][4096][64] fp16
    u16* Vb = Kb + (size_t)QKV_ELEMS;
    float* norms = (float*)(Vb + (size_t)QKV_ELEMS);  // [32][4096] fp32
    int* gidx = (int*)(norms + (size_t)NHT * TT);     // [32][1024]
    int* lidx = gidx + (size_t)NHT * 1024;            // [32][3072]

    qv_gemm<<<dim3(64, 8, 2), 256, 0, stream>>>(H, Wq, Wv, bq, bv, out, Vb);
    k_gemm<<<dim3(64, 8), 256, 0, stream>>>(H, Wk, bk, bq, Kb, norms);
    select_topk<<<NHT * 64, 64, 0, stream>>>(norms, mask, gidx, lidx);
    bos_kernel<<<NHT, 64, 0, stream>>>(Kb, Vb, mask, out);
    attn_kernel<<<NHT * 64, 64, 0, stream>>>(Kb, Vb, gidx, lidx, mask, out);
}

// Round 5
// 628.171 us; speedup vs baseline: 1.4287x; 1.4287x over previous
//
#include <hip/hip_runtime.h>
#include <hip/hip_bf16.h>

typedef unsigned short u16;
typedef __attribute__((ext_vector_type(4))) float f32x4;
typedef __attribute__((ext_vector_type(8))) _Float16 f16x8;
typedef __attribute__((ext_vector_type(4))) _Float16 f16x4;
typedef __attribute__((ext_vector_type(2))) _Float16 h2;

// dims
#define NB 2
#define TT 4096
#define HID 1024
#define NHEAD 16
#define DH 64
#define NHT (NB * NHEAD)          // 32
#define QKV_ELEMS (NHT * TT * DH) // 8388608 per tensor
#define LO_SCALE 2048.0f          // 2^11
#define LO_INV   4.8828125e-4f    // 2^-11

__device__ __forceinline__ float dot2(h2 a, h2 b, float c) {
#if __has_builtin(__builtin_amdgcn_fdot2)
    return __builtin_amdgcn_fdot2(a, b, c, false);
#else
    return fmaf((float)a[0], (float)b[0], fmaf((float)a[1], (float)b[1], c));
#endif
}

// ---------------------------------------------------------------------------
// Kernel A: Q and V projection (fp32 in, fp16 MFMA, fp32/fp16 out).
// z=0: Q -> d_out (fp32, final [n,t,h,d] layout, reused as q storage)
// z=1: V -> ws (fp16, [nh,t,d])
// ---------------------------------------------------------------------------
__global__ __launch_bounds__(256) void qv_gemm(
    const float* __restrict__ H,
    const float* __restrict__ Wq, const float* __restrict__ Wv,
    const float* __restrict__ bq, const float* __restrict__ bv,
    float* __restrict__ qout, u16* __restrict__ vout)
{
    const int z = blockIdx.z;
    const float* W    = (z == 0) ? Wq : Wv;
    const float* bias = (z == 0) ? bq : bv;

    __shared__ __align__(16) u16 Ah[128 * 32];
    __shared__ __align__(16) u16 Bh[128 * 32];

    const int tid  = threadIdx.x;
    const int lane = tid & 63;
    const int wid  = tid >> 6;
    const int wm = (wid >> 1) * 64;
    const int wn = (wid & 1) * 64;
    const int bm = blockIdx.x * 128;
    const int bn = blockIdx.y * 128;
    const int l15 = lane & 15, l4 = lane >> 4;

    f32x4 acc[4][4] = {};

    for (int k0 = 0; k0 < 1024; k0 += 32) {
#pragma unroll
        for (int it = 0; it < 4; it++) {
            int c = it * 256 + tid;
            int row = c >> 3;
            int col = (c & 7) * 4;
            f32x4 a = *(const f32x4*)&H[(size_t)(bm + row) * 1024 + k0 + col];
            f32x4 b = *(const f32x4*)&W[(size_t)(bn + row) * 1024 + k0 + col];
            f16x4 ah, bh;
#pragma unroll
            for (int u = 0; u < 4; u++) { ah[u] = (_Float16)a[u]; bh[u] = (_Float16)b[u]; }
            *(f16x4*)&Ah[row * 32 + col] = ah;
            *(f16x4*)&Bh[row * 32 + col] = bh;
        }
        __syncthreads();

        f16x8 aF[4], bF[4];
#pragma unroll
        for (int i = 0; i < 4; i++) {
            aF[i] = *(const f16x8*)&Ah[(wm + i * 16 + l15) * 32 + l4 * 8];
            bF[i] = *(const f16x8*)&Bh[(wn + i * 16 + l15) * 32 + l4 * 8];
        }
#pragma unroll
        for (int i = 0; i < 4; i++)
#pragma unroll
            for (int j = 0; j < 4; j++)
                acc[i][j] = __builtin_amdgcn_mfma_f32_16x16x32_f16(aF[i], bF[j], acc[i][j], 0, 0, 0);
        __syncthreads();
    }

    float bvj[4];
#pragma unroll
    for (int j = 0; j < 4; j++) bvj[j] = bias[bn + wn + j * 16 + l15];

#pragma unroll
    for (int i = 0; i < 4; i++) {
#pragma unroll
        for (int j = 0; j < 4; j++) {
            int col = bn + wn + j * 16 + l15;   // h*64 + d
            int hh = col >> 6, dd = col & 63;
#pragma unroll
            for (int r = 0; r < 4; r++) {
                int m = bm + wm + i * 16 + l4 * 4 + r;   // n*T + t
                float v = acc[i][j][r] + bvj[j];
                if (z == 0) {
                    qout[(size_t)m * HID + col] = v;
                } else {
                    int nbat = m >> 12, t = m & 4095;
                    _Float16 hv = (_Float16)v;
                    vout[(((size_t)(nbat * NHEAD + hh)) * TT + t) * DH + dd] =
                        *(u16*)&hv;
                }
            }
        }
    }
}

// ---------------------------------------------------------------------------
// Kernel B: K projection with 2-term fp16 split (hi + 2^11*lo), 3 MFMAs.
// Near-fp32 accuracy so the norm-based top-k ordering matches the np ref.
// ---------------------------------------------------------------------------
__global__ __launch_bounds__(256) void k_gemm(
    const float* __restrict__ H, const float* __restrict__ Wk,
    const float* __restrict__ bk, const float* __restrict__ bq,
    u16* __restrict__ kout, float* __restrict__ norms)
{
    __shared__ __align__(16) u16 Ah[128 * 32];
    __shared__ __align__(16) u16 Al[128 * 32];
    __shared__ __align__(16) u16 Bh[128 * 32];
    __shared__ __align__(16) u16 Bl[128 * 32];

    const int tid  = threadIdx.x;
    const int lane = tid & 63;
    const int wid  = tid >> 6;
    const int wm = (wid >> 1) * 64;
    const int wn = (wid & 1) * 64;
    const int bm = blockIdx.x * 128;
    const int bn = blockIdx.y * 128;
    const int l15 = lane & 15, l4 = lane >> 4;

    f32x4 accM[4][4] = {};
    f32x4 accC[4][4] = {};

    for (int k0 = 0; k0 < 1024; k0 += 32) {
#pragma unroll
        for (int it = 0; it < 4; it++) {
            int c = it * 256 + tid;
            int row = c >> 3;
            int col = (c & 7) * 4;
            f32x4 a = *(const f32x4*)&H[(size_t)(bm + row) * 1024 + k0 + col];
            f32x4 b = *(const f32x4*)&Wk[(size_t)(bn + row) * 1024 + k0 + col];
            f16x4 ah, al, bh, bl;
#pragma unroll
            for (int u = 0; u < 4; u++) {
                _Float16 hh = (_Float16)a[u];
                ah[u] = hh; al[u] = (_Float16)((a[u] - (float)hh) * LO_SCALE);
                _Float16 g = (_Float16)b[u];
                bh[u] = g; bl[u] = (_Float16)((b[u] - (float)g) * LO_SCALE);
            }
            *(f16x4*)&Ah[row * 32 + col] = ah;
            *(f16x4*)&Al[row * 32 + col] = al;
            *(f16x4*)&Bh[row * 32 + col] = bh;
            *(f16x4*)&Bl[row * 32 + col] = bl;
        }
        __syncthreads();

        f16x8 aH[4], aL[4], bH[4], bL[4];
#pragma unroll
        for (int i = 0; i < 4; i++) {
            int ao = (wm + i * 16 + l15) * 32 + l4 * 8;
            int bo = (wn + i * 16 + l15) * 32 + l4 * 8;
            aH[i] = *(const f16x8*)&Ah[ao];
            aL[i] = *(const f16x8*)&Al[ao];
            bH[i] = *(const f16x8*)&Bh[bo];
            bL[i] = *(const f16x8*)&Bl[bo];
        }
#pragma unroll
        for (int i = 0; i < 4; i++)
#pragma unroll
            for (int j = 0; j < 4; j++) {
                accM[i][j] = __builtin_amdgcn_mfma_f32_16x16x32_f16(aH[i], bH[j], accM[i][j], 0, 0, 0);
                accC[i][j] = __builtin_amdgcn_mfma_f32_16x16x32_f16(aH[i], bL[j], accC[i][j], 0, 0, 0);
                accC[i][j] = __builtin_amdgcn_mfma_f32_16x16x32_f16(aL[i], bH[j], accC[i][j], 0, 0, 0);
            }
        __syncthreads();
    }

    float bkj[4], bqj[4];
#pragma unroll
    for (int j = 0; j < 4; j++) {
        bkj[j] = bk[bn + wn + j * 16 + l15];
        bqj[j] = bq[bn + wn + j * 16 + l15];
    }

#pragma unroll
    for (int i = 0; i < 4; i++) {
#pragma unroll
        for (int r = 0; r < 4; r++) {
            int m = bm + wm + i * 16 + l4 * 4 + r;
            int nbat = m >> 12, t = m & 4095;
            float sq = 0.f;
#pragma unroll
            for (int j = 0; j < 4; j++) {
                int col = bn + wn + j * 16 + l15;
                int hh = col >> 6, dd = col & 63;
                float kv = accM[i][j][r] + accC[i][j][r] * LO_INV + bkj[j];
                _Float16 hv = (_Float16)kv;
                kout[(((size_t)(nbat * NHEAD + hh)) * TT + t) * DH + dd] = *(u16*)&hv;
                float x = kv + bqj[j];
                sq = fmaf(x, x, sq);
            }
            sq += __shfl_xor(sq, 1);
            sq += __shfl_xor(sq, 2);
            sq += __shfl_xor(sq, 4);
            sq += __shfl_xor(sq, 8);
            if (l15 == 0) {
                int hh = (bn + wn) >> 6;
                norms[((size_t)(nbat * NHEAD + hh)) * TT + t] = sq;
            }
        }
    }
}

// ---------------------------------------------------------------------------
// Kernel C: norm-based top-k per 64-token chunk (stable rank by (norm, idx)).
// ---------------------------------------------------------------------------
__global__ __launch_bounds__(64) void select_topk(
    const float* __restrict__ norms_in, const float* __restrict__ mask,
    int* __restrict__ gidx, int* __restrict__ lidx)
{
    const int bid = blockIdx.x;          // nh*64 + c
    const int nh = bid >> 6, c = bid & 63;
    const int n = nh >> 4;
    const int tid = threadIdx.x;
    const int tok = c * 64 + tid;

    float nrm = norms_in[(size_t)nh * TT + tok];
    if (nrm != nrm) nrm = 0.f;                       // NaN guard
    if (mask[(size_t)n * TT + tok] != 0.f) nrm = 0.f;

    __shared__ float norms[64];
    __shared__ int flags[64];
    norms[tid] = nrm;
    __syncthreads();

    int rank = 0;
    for (int j = 0; j < 64; j++) {
        float nj = norms[j];
        rank += (nj < nrm || (nj == nrm && j < tid)) ? 1 : 0;
    }
    int istop = (rank >= 48) ? 1 : 0;
    flags[tid] = istop;
    __syncthreads();

    int pos = 0;
    for (int j = 0; j < tid; j++) pos += istop ? flags[j] : (1 - flags[j]);
    if (istop) gidx[(size_t)nh * 1024 + c * 16 + pos] = tok;
    else       lidx[(size_t)nh * 3072 + c * 48 + pos] = tok;
}

// ---------------------------------------------------------------------------
// Kernel D: BOS token — full UNSCALED attention over all keys; writes t=0.
// ---------------------------------------------------------------------------
__global__ __launch_bounds__(64) void bos_kernel(
    const u16* __restrict__ K, const u16* __restrict__ V,
    const float* __restrict__ mask, float* __restrict__ out)
{
    const int nh = blockIdx.x;
    const int n = nh >> 4, h = nh & 15;
    const int tid = threadIdx.x;
    const size_t base = (size_t)nh * TT * DH;

    float q[64];
    {
        const float* qr = out + ((size_t)n * TT) * HID + h * 64;
#pragma unroll
        for (int i = 0; i < 16; i++) {
            f32x4 v = *(const f32x4*)&qr[i * 4];
#pragma unroll
            for (int u = 0; u < 4; u++) q[i * 4 + u] = v[u];
        }
    }

    float m_ = -1e30f, l_ = 0.f, acc[64];
#pragma unroll
    for (int d = 0; d < 64; d++) acc[d] = 0.f;

    for (int kk = tid; kk < TT; kk += 64) {
        const u16* kr = K + base + (size_t)kk * DH;
        const u16* vr = V + base + (size_t)kk * DH;
        float s = 0.f;
#pragma unroll
        for (int i = 0; i < 8; i++) {
            f16x8 kv = *(const f16x8*)&kr[i * 8];
#pragma unroll
            for (int u = 0; u < 8; u++) s = fmaf(q[i * 8 + u], (float)kv[u], s);
        }
        s += mask[(size_t)n * TT + kk];   // unscaled
        float mn = fmaxf(m_, s);
        float sc = __expf(m_ - mn);
        float p  = __expf(s - mn);
        l_ = l_ * sc + p;
#pragma unroll
        for (int i = 0; i < 8; i++) {
            f16x8 vv = *(const f16x8*)&vr[i * 8];
#pragma unroll
            for (int u = 0; u < 8; u++)
                acc[i * 8 + u] = fmaf(acc[i * 8 + u], sc, p * (float)vv[u]);
        }
        m_ = mn;
    }

    __shared__ float ms[64], ls[64], accs[64][65];
    ms[tid] = m_; ls[tid] = l_;
#pragma unroll
    for (int d = 0; d < 64; d++) accs[tid][d] = acc[d];
    __syncthreads();

    float M = -1e30f;
    for (int j = 0; j < 64; j++) M = fmaxf(M, ms[j]);
    float L = 0.f;
    for (int j = 0; j < 64; j++) L += ls[j] * __expf(ms[j] - M);
    float sum = 0.f;
    for (int j = 0; j < 64; j++) sum = fmaf(accs[j][tid], __expf(ms[j] - M), sum);
    out[((size_t)n * TT) * HID + h * 64 + tid] = sum / L;
}

// ---------------------------------------------------------------------------
// Kernel E: fused selected-global + local attention + lse merge.
// Block = 256 threads (4 waves) per (nh, 64-query chunk). Lane = query.
// The 4 waves split the key stream (stride-4 within each segment), each
// keeps an online-softmax partial state, merged through LDS per pass.
// Keys are scored in batches of 4 (ILP + amortized rescale), QK via dot2.
// ---------------------------------------------------------------------------
__global__ __launch_bounds__(256) void attn_kernel(
    const u16* __restrict__ K, const u16* __restrict__ V,
    const int* __restrict__ gidx, const int* __restrict__ lidx,
    const float* __restrict__ mask, float* __restrict__ out)
{
    const int bid = blockIdx.x;
    const int nh = bid >> 6, c = bid & 63;
    const int n = nh >> 4, h = nh & 15;
    const int tid = threadIdx.x;
    const int wid = tid >> 6, lane = tid & 63;
    const int t = c * 64 + lane;
    const size_t kvbase = (size_t)nh * TT * DH;
    const float* maskrow = mask + (size_t)n * TT;

    // each wave loads the same 64 q rows (lane = query), packed to f16 pairs
    h2 q2[32];
    {
        const f32x4* q4 = (const f32x4*)(out + ((size_t)n * TT + t) * HID + h * 64);
#pragma unroll
        for (int i = 0; i < 16; i++) {
            f32x4 v = q4[i];
            h2 a; a[0] = (_Float16)v[0]; a[1] = (_Float16)v[1];
            h2 b; b[0] = (_Float16)v[2]; b[1] = (_Float16)v[3];
            q2[i * 2] = a; q2[i * 2 + 1] = b;
        }
    }

    __shared__ float bufG[64 * 65];
    __shared__ float bufL[64 * 65];
    __shared__ float msx[4 * 64], lsx[4 * 64];
    __shared__ float lseG[64], LinvG[64], lseL[64], LinvL[64];

    float m_ = -1e30f, l_ = 0.f;
    float acc[64];
#pragma unroll
    for (int d = 0; d < 64; d++) acc[d] = 0.f;

    // batch of 4 keys (wave-uniform indices)
    auto batch4 = [&](int k0i, int k1i, int k2i, int k3i) {
        const h2* k0p = (const h2*)(K + kvbase + (size_t)k0i * DH);
        const h2* k1p = (const h2*)(K + kvbase + (size_t)k1i * DH);
        const h2* k2p = (const h2*)(K + kvbase + (size_t)k2i * DH);
        const h2* k3p = (const h2*)(K + kvbase + (size_t)k3i * DH);
        float s0 = 0.f, s1 = 0.f, s2 = 0.f, s3 = 0.f;
#pragma unroll
        for (int i = 0; i < 32; i++) {
            s0 = dot2(q2[i], k0p[i], s0);
            s1 = dot2(q2[i], k1p[i], s1);
            s2 = dot2(q2[i], k2p[i], s2);
            s3 = dot2(q2[i], k3p[i], s3);
        }
        s0 = fmaf(s0, 0.125f, maskrow[k0i]);
        s1 = fmaf(s1, 0.125f, maskrow[k1i]);
        s2 = fmaf(s2, 0.125f, maskrow[k2i]);
        s3 = fmaf(s3, 0.125f, maskrow[k3i]);
        float bm = fmaxf(fmaxf(s0, s1), fmaxf(s2, s3));
        float mn = fmaxf(m_, bm);
        float sc = __expf(m_ - mn);
        float p0 = __expf(s0 - mn), p1 = __expf(s1 - mn);
        float p2 = __expf(s2 - mn), p3 = __expf(s3 - mn);
        l_ = fmaf(l_, sc, (p0 + p1) + (p2 + p3));
        const f16x8* v0p = (const f16x8*)(V + kvbase + (size_t)k0i * DH);
        const f16x8* v1p = (const f16x8*)(V + kvbase + (size_t)k1i * DH);
        const f16x8* v2p = (const f16x8*)(V + kvbase + (size_t)k2i * DH);
        const f16x8* v3p = (const f16x8*)(V + kvbase + (size_t)k3i * DH);
#pragma unroll
        for (int ch = 0; ch < 8; ch++) {
            f16x8 a = v0p[ch], b = v1p[ch], cc = v2p[ch], dd2 = v3p[ch];
#pragma unroll
            for (int u = 0; u < 8; u++) {
                int dd = ch * 8 + u;
                float pv = fmaf(p0, (float)a[u],
                           fmaf(p1, (float)b[u],
                           fmaf(p2, (float)cc[u], p3 * (float)dd2[u])));
                acc[dd] = fmaf(acc[dd], sc, pv);
            }
        }
        m_ = mn;
    };

    // single-key step (for the appended global key 0)
    auto step1 = [&](int key, float madd) {
        const h2* kp = (const h2*)(K + kvbase + (size_t)key * DH);
        float s = 0.f;
#pragma unroll
        for (int i = 0; i < 32; i++) s = dot2(q2[i], kp[i], s);
        s = fmaf(s, 0.125f, madd);
        float mn = fmaxf(m_, s);
        float sc = __expf(m_ - mn);
        float p  = __expf(s - mn);
        l_ = fmaf(l_, sc, p);
        const f16x8* vp = (const f16x8*)(V + kvbase + (size_t)key * DH);
#pragma unroll
        for (int ch = 0; ch < 8; ch++) {
            f16x8 vv = vp[ch];
#pragma unroll
            for (int u = 0; u < 8; u++) {
                int dd = ch * 8 + u;
                acc[dd] = fmaf(acc[dd], sc, p * (float)vv[u]);
            }
        }
        m_ = mn;
    };

    // merge 4 wave-partial states through LDS into buf; record lse, 1/L
    auto merge = [&](float* buf, float* lse, float* Linv) {
        msx[wid * 64 + lane] = m_; lsx[wid * 64 + lane] = l_;
        __syncthreads();
        float M = fmaxf(fmaxf(msx[lane], msx[64 + lane]),
                        fmaxf(msx[128 + lane], msx[192 + lane]));
        float L = lsx[lane] * __expf(msx[lane] - M)
                + lsx[64 + lane] * __expf(msx[64 + lane] - M)
                + lsx[128 + lane] * __expf(msx[128 + lane] - M)
                + lsx[192 + lane] * __expf(msx[192 + lane] - M);
        float f = __expf(m_ - M);
        for (int w = 0; w < 4; w++) {
            if (wid == w) {
                if (w == 0) {
#pragma unroll
                    for (int d = 0; d < 64; d++) buf[lane * 65 + d] = acc[d] * f;
                } else {
#pragma unroll
                    for (int d = 0; d < 64; d++) buf[lane * 65 + d] += acc[d] * f;
                }
            }
            __syncthreads();
        }
        if (wid == 0) { lse[lane] = M + __logf(L); Linv[lane] = 1.f / L; }
        __syncthreads();
    };

    // ---- global (selected) pass: 3 segments x 16 keys; wave takes {wid+4j}
    const int* gp = gidx + (size_t)nh * 1024;
    for (int w3 = -1; w3 <= 1; w3++) {
        int blk = c + w3;
        if (blk < 0 || blk >= 64) continue;
        const int* seg = gp + blk * 16;
        int k0i = __builtin_amdgcn_readfirstlane(seg[wid])      & 4095;
        int k1i = __builtin_amdgcn_readfirstlane(seg[wid + 4])  & 4095;
        int k2i = __builtin_amdgcn_readfirstlane(seg[wid + 8])  & 4095;
        int k3i = __builtin_amdgcn_readfirstlane(seg[wid + 12]) & 4095;
        batch4(k0i, k1i, k2i, k3i);
    }
    merge(bufG, lseG, LinvG);

    // ---- local pass: key 0 (wave 0) + 3 segments x 96 keys
    m_ = -1e30f; l_ = 0.f;
#pragma unroll
    for (int d = 0; d < 64; d++) acc[d] = 0.f;

    if (wid == 0) step1(0, 0.f);
    int bl = c >> 1;
    const int* lp = lidx + (size_t)nh * 3072;
    for (int w3 = -1; w3 <= 1; w3++) {
        int blk = bl + w3;
        if (blk < 0 || blk >= 32) continue;
        const int* seg = lp + blk * 96;
#pragma unroll 1
        for (int b = 0; b < 6; b++) {
            int base = wid + 16 * b;
            int k0i = __builtin_amdgcn_readfirstlane(seg[base])      & 4095;
            int k1i = __builtin_amdgcn_readfirstlane(seg[base + 4])  & 4095;
            int k2i = __builtin_amdgcn_readfirstlane(seg[base + 8])  & 4095;
            int k3i = __builtin_amdgcn_readfirstlane(seg[base + 12]) & 4095;
            batch4(k0i, k1i, k2i, k3i);
        }
    }
    merge(bufL, lseL, LinvL);

    // ---- final combine + store (thread -> quarter-row of query q)
    {
        int q = tid >> 2;
        int dq = (tid & 3) * 16;
        int tq = c * 64 + q;
        if (tq != 0) {   // t=0 row holds the bos result — keep it
            float p = 1.f / (1.f + __expf(lseG[q] - lseL[q]));
            float lg = LinvG[q], ll = LinvL[q];
            size_t ob = ((size_t)n * TT + tq) * HID + h * 64 + dq;
#pragma unroll
            for (int u = 0; u < 16; u++) {
                float cg = bufG[q * 65 + dq + u] * lg;
                float cl = bufL[q * 65 + dq + u] * ll;
                out[ob + u] = cg + p * (cl - cg);
            }
        }
    }
}

// ---------------------------------------------------------------------------
__global__ void ws_sentinel(float* out, int n, float val) {
    int i = blockIdx.x * 256 + threadIdx.x;
    if (i < n) out[i] = val;
}

// ---------------------------------------------------------------------------
extern "C" void kernel_launch(void* const* d_in, const int* in_sizes, int n_in,
                              void* d_out, int out_size, void* d_ws, size_t ws_size,
                              hipStream_t stream) {
    int iH = 0, iM = 1, iW[3] = {2, 4, 6}, ib[3] = {3, 5, 7};
    {
        int nw = 0, nb2 = 0, seenH = 0, seenM = 0;
        for (int i = 0; i < n_in; i++) {
            int s = in_sizes[i];
            if (s == 8388608 && !seenH) { iH = i; seenH = 1; }
            else if (s == 8192 && !seenM) { iM = i; seenM = 1; }
            else if (s == 1048576 && nw < 3) iW[nw++] = i;
            else if (s == 1024 && nb2 < 3) ib[nb2++] = i;
        }
    }
    const float* H    = (const float*)d_in[iH];
    const float* mask = (const float*)d_in[iM];
    const float* Wq = (const float*)d_in[iW[0]];
    const float* Wk = (const float*)d_in[iW[1]];
    const float* Wv = (const float*)d_in[iW[2]];
    const float* bq = (const float*)d_in[ib[0]];
    const float* bk = (const float*)d_in[ib[1]];
    const float* bv = (const float*)d_in[ib[2]];
    float* out = (float*)d_out;

    const size_t WS_NEED = (size_t)2 * QKV_ELEMS * 2 + (size_t)NHT * TT * 4
                         + (size_t)NHT * 1024 * 4 + (size_t)NHT * 3072 * 4;
    if (ws_size < WS_NEED) {
        float val = (float)(ws_size >> 20);
        ws_sentinel<<<(out_size + 255) / 256, 256, 0, stream>>>(out, out_size, val);
        return;
    }

    u16* Kb = (u16*)d_ws;                             // [32][4096][64] fp16
    u16* Vb = Kb + (size_t)QKV_ELEMS;
    float* norms = (float*)(Vb + (size_t)QKV_ELEMS);  // [32][4096] fp32
    int* gidx = (int*)(norms + (size_t)NHT * TT);     // [32][1024]
    int* lidx = gidx + (size_t)NHT * 1024;            // [32][3072]

    qv_gemm<<<dim3(64, 8, 2), 256, 0, stream>>>(H, Wq, Wv, bq, bv, out, Vb);
    k_gemm<<<dim3(64, 8), 256, 0, stream>>>(H, Wk, bk, bq, Kb, norms);
    select_topk<<<NHT * 64, 64, 0, stream>>>(norms, mask, gidx, lidx);
    bos_kernel<<<NHT, 64, 0, stream>>>(Kb, Vb, mask, out);
    attn_kernel<<<NHT * 64, 256, 0, stream>>>(Kb, Vb, gidx, lidx, mask, out);
}

// Round 6
// 577.407 us; speedup vs baseline: 1.5543x; 1.0879x over previous
//
#include <hip/hip_runtime.h>
#include <hip/hip_bf16.h>

typedef unsigned short u16;
typedef __attribute__((ext_vector_type(4))) float f32x4;
typedef __attribute__((ext_vector_type(8))) _Float16 f16x8;
typedef __attribute__((ext_vector_type(4))) _Float16 f16x4;
typedef __attribute__((ext_vector_type(2))) _Float16 h2;

// dims
#define NB 2
#define TT 4096
#define HID 1024
#define NHEAD 16
#define DH 64
#define NHT (NB * NHEAD)          // 32
#define QKV_ELEMS (NHT * TT * DH) // 8388608 per tensor
#define LO_SCALE 2048.0f          // 2^11
#define LO_INV   4.8828125e-4f    // 2^-11

union U8 { uint4 u; h2 h[4]; f16x8 v; };

__device__ __forceinline__ float dot2(h2 a, h2 b, float c) {
#if __has_builtin(__builtin_amdgcn_fdot2)
    return __builtin_amdgcn_fdot2(a, b, c, false);
#else
    return fmaf((float)a[0], (float)b[0], fmaf((float)a[1], (float)b[1], c));
#endif
}

// ---------------------------------------------------------------------------
// Pre-conversion kernels (extended-ws path): fp32 -> fp16 hi (+ 2^11*lo)
// ---------------------------------------------------------------------------
__global__ __launch_bounds__(256) void conv_split(
    const float* __restrict__ src, u16* __restrict__ hi, u16* __restrict__ lo, int n4)
{
    int i = blockIdx.x * 256 + threadIdx.x;
    if (i >= n4) return;
    f32x4 x = ((const f32x4*)src)[i];
    f16x4 h, l;
#pragma unroll
    for (int u = 0; u < 4; u++) {
        _Float16 hh = (_Float16)x[u];
        h[u] = hh;
        l[u] = (_Float16)((x[u] - (float)hh) * LO_SCALE);
    }
    ((f16x4*)hi)[i] = h;
    ((f16x4*)lo)[i] = l;
}

__global__ __launch_bounds__(256) void conv_hi(
    const float* __restrict__ src, u16* __restrict__ hi, int n4)
{
    int i = blockIdx.x * 256 + threadIdx.x;
    if (i >= n4) return;
    f32x4 x = ((const f32x4*)src)[i];
    f16x4 h;
#pragma unroll
    for (int u = 0; u < 4; u++) h[u] = (_Float16)x[u];
    ((f16x4*)hi)[i] = h;
}

// ---------------------------------------------------------------------------
// Kernel A16: Q and V projection from PRE-CONVERTED fp16 inputs.
// z=0: Q -> d_out (fp32, [n,t,h,d]); z=1: V -> ws (fp16, [nh,t,d]).
// ---------------------------------------------------------------------------
__global__ __launch_bounds__(256) void qv_gemm16(
    const u16* __restrict__ H16,
    const u16* __restrict__ Wq16, const u16* __restrict__ Wv16,
    const float* __restrict__ bq, const float* __restrict__ bv,
    float* __restrict__ qout, u16* __restrict__ vout)
{
    const int z = blockIdx.z;
    const u16* W    = (z == 0) ? Wq16 : Wv16;
    const float* bias = (z == 0) ? bq : bv;

    __shared__ __align__(16) u16 At[128 * 32];
    __shared__ __align__(16) u16 Bt[128 * 32];

    const int tid  = threadIdx.x;
    const int lane = tid & 63;
    const int wid  = tid >> 6;
    const int wm = (wid >> 1) * 64;
    const int wn = (wid & 1) * 64;
    const int bm = blockIdx.x * 128;
    const int bn = blockIdx.y * 128;
    const int l15 = lane & 15, l4 = lane >> 4;

    f32x4 acc[4][4] = {};

    for (int k0 = 0; k0 < 1024; k0 += 32) {
#pragma unroll
        for (int h2i = 0; h2i < 2; h2i++) {
            int c = h2i * 256 + tid;           // 512 16B-chunks per tile
            int row = c >> 2;
            int kc  = (c & 3) * 8;
            *(uint4*)&At[c * 8] = *(const uint4*)&H16[(size_t)(bm + row) * 1024 + k0 + kc];
            *(uint4*)&Bt[c * 8] = *(const uint4*)&W[(size_t)(bn + row) * 1024 + k0 + kc];
        }
        __syncthreads();

        f16x8 aF[4], bF[4];
#pragma unroll
        for (int i = 0; i < 4; i++) {
            aF[i] = *(const f16x8*)&At[(wm + i * 16 + l15) * 32 + l4 * 8];
            bF[i] = *(const f16x8*)&Bt[(wn + i * 16 + l15) * 32 + l4 * 8];
        }
#pragma unroll
        for (int i = 0; i < 4; i++)
#pragma unroll
            for (int j = 0; j < 4; j++)
                acc[i][j] = __builtin_amdgcn_mfma_f32_16x16x32_f16(aF[i], bF[j], acc[i][j], 0, 0, 0);
        __syncthreads();
    }

    float bvj[4];
#pragma unroll
    for (int j = 0; j < 4; j++) bvj[j] = bias[bn + wn + j * 16 + l15];

#pragma unroll
    for (int i = 0; i < 4; i++) {
#pragma unroll
        for (int j = 0; j < 4; j++) {
            int col = bn + wn + j * 16 + l15;   // h*64 + d
            int hh = col >> 6, dd = col & 63;
#pragma unroll
            for (int r = 0; r < 4; r++) {
                int m = bm + wm + i * 16 + l4 * 4 + r;   // n*T + t
                float v = acc[i][j][r] + bvj[j];
                if (z == 0) {
                    qout[(size_t)m * HID + col] = v;
                } else {
                    int nbat = m >> 12, t = m & 4095;
                    _Float16 hv = (_Float16)v;
                    vout[(((size_t)(nbat * NHEAD + hh)) * TT + t) * DH + dd] = *(u16*)&hv;
                }
            }
        }
    }
}

// ---------------------------------------------------------------------------
// Kernel B16: K projection from pre-split fp16 inputs (hi + 2^11*lo), 3 MFMAs.
// ---------------------------------------------------------------------------
__global__ __launch_bounds__(256) void k_gemm16(
    const u16* __restrict__ Hh, const u16* __restrict__ Hl,
    const u16* __restrict__ Wkh, const u16* __restrict__ Wkl,
    const float* __restrict__ bk, const float* __restrict__ bq,
    u16* __restrict__ kout, float* __restrict__ norms)
{
    __shared__ __align__(16) u16 Ah[128 * 32];
    __shared__ __align__(16) u16 Al[128 * 32];
    __shared__ __align__(16) u16 Bh[128 * 32];
    __shared__ __align__(16) u16 Bl[128 * 32];

    const int tid  = threadIdx.x;
    const int lane = tid & 63;
    const int wid  = tid >> 6;
    const int wm = (wid >> 1) * 64;
    const int wn = (wid & 1) * 64;
    const int bm = blockIdx.x * 128;
    const int bn = blockIdx.y * 128;
    const int l15 = lane & 15, l4 = lane >> 4;

    f32x4 accM[4][4] = {};
    f32x4 accC[4][4] = {};

    for (int k0 = 0; k0 < 1024; k0 += 32) {
#pragma unroll
        for (int h2i = 0; h2i < 2; h2i++) {
            int c = h2i * 256 + tid;
            int row = c >> 2;
            int kc  = (c & 3) * 8;
            size_t ga = (size_t)(bm + row) * 1024 + k0 + kc;
            size_t gb = (size_t)(bn + row) * 1024 + k0 + kc;
            *(uint4*)&Ah[c * 8] = *(const uint4*)&Hh[ga];
            *(uint4*)&Al[c * 8] = *(const uint4*)&Hl[ga];
            *(uint4*)&Bh[c * 8] = *(const uint4*)&Wkh[gb];
            *(uint4*)&Bl[c * 8] = *(const uint4*)&Wkl[gb];
        }
        __syncthreads();

        f16x8 aH[4], aL[4], bH[4], bL[4];
#pragma unroll
        for (int i = 0; i < 4; i++) {
            int ao = (wm + i * 16 + l15) * 32 + l4 * 8;
            int bo = (wn + i * 16 + l15) * 32 + l4 * 8;
            aH[i] = *(const f16x8*)&Ah[ao];
            aL[i] = *(const f16x8*)&Al[ao];
            bH[i] = *(const f16x8*)&Bh[bo];
            bL[i] = *(const f16x8*)&Bl[bo];
        }
#pragma unroll
        for (int i = 0; i < 4; i++)
#pragma unroll
            for (int j = 0; j < 4; j++) {
                accM[i][j] = __builtin_amdgcn_mfma_f32_16x16x32_f16(aH[i], bH[j], accM[i][j], 0, 0, 0);
                accC[i][j] = __builtin_amdgcn_mfma_f32_16x16x32_f16(aH[i], bL[j], accC[i][j], 0, 0, 0);
                accC[i][j] = __builtin_amdgcn_mfma_f32_16x16x32_f16(aL[i], bH[j], accC[i][j], 0, 0, 0);
            }
        __syncthreads();
    }

    float bkj[4], bqj[4];
#pragma unroll
    for (int j = 0; j < 4; j++) {
        bkj[j] = bk[bn + wn + j * 16 + l15];
        bqj[j] = bq[bn + wn + j * 16 + l15];
    }

#pragma unroll
    for (int i = 0; i < 4; i++) {
#pragma unroll
        for (int r = 0; r < 4; r++) {
            int m = bm + wm + i * 16 + l4 * 4 + r;
            int nbat = m >> 12, t = m & 4095;
            float sq = 0.f;
#pragma unroll
            for (int j = 0; j < 4; j++) {
                int col = bn + wn + j * 16 + l15;
                int hh = col >> 6, dd = col & 63;
                float kv = accM[i][j][r] + accC[i][j][r] * LO_INV + bkj[j];
                _Float16 hv = (_Float16)kv;
                kout[(((size_t)(nbat * NHEAD + hh)) * TT + t) * DH + dd] = *(u16*)&hv;
                float x = kv + bqj[j];
                sq = fmaf(x, x, sq);
            }
            sq += __shfl_xor(sq, 1);
            sq += __shfl_xor(sq, 2);
            sq += __shfl_xor(sq, 4);
            sq += __shfl_xor(sq, 8);
            if (l15 == 0) {
                int hh = (bn + wn) >> 6;
                norms[((size_t)(nbat * NHEAD + hh)) * TT + t] = sq;
            }
        }
    }
}

// ---------------------------------------------------------------------------
// FALLBACK GEMMs (fp32 staging + convert) — proven R5 path, used if ws small.
// ---------------------------------------------------------------------------
__global__ __launch_bounds__(256) void qv_gemm(
    const float* __restrict__ H,
    const float* __restrict__ Wq, const float* __restrict__ Wv,
    const float* __restrict__ bq, const float* __restrict__ bv,
    float* __restrict__ qout, u16* __restrict__ vout)
{
    const int z = blockIdx.z;
    const float* W    = (z == 0) ? Wq : Wv;
    const float* bias = (z == 0) ? bq : bv;

    __shared__ __align__(16) u16 Ah[128 * 32];
    __shared__ __align__(16) u16 Bh[128 * 32];

    const int tid  = threadIdx.x;
    const int lane = tid & 63;
    const int wid  = tid >> 6;
    const int wm = (wid >> 1) * 64;
    const int wn = (wid & 1) * 64;
    const int bm = blockIdx.x * 128;
    const int bn = blockIdx.y * 128;
    const int l15 = lane & 15, l4 = lane >> 4;

    f32x4 acc[4][4] = {};

    for (int k0 = 0; k0 < 1024; k0 += 32) {
#pragma unroll
        for (int it = 0; it < 4; it++) {
            int c = it * 256 + tid;
            int row = c >> 3;
            int col = (c & 7) * 4;
            f32x4 a = *(const f32x4*)&H[(size_t)(bm + row) * 1024 + k0 + col];
            f32x4 b = *(const f32x4*)&W[(size_t)(bn + row) * 1024 + k0 + col];
            f16x4 ah, bh;
#pragma unroll
            for (int u = 0; u < 4; u++) { ah[u] = (_Float16)a[u]; bh[u] = (_Float16)b[u]; }
            *(f16x4*)&Ah[row * 32 + col] = ah;
            *(f16x4*)&Bh[row * 32 + col] = bh;
        }
        __syncthreads();

        f16x8 aF[4], bF[4];
#pragma unroll
        for (int i = 0; i < 4; i++) {
            aF[i] = *(const f16x8*)&Ah[(wm + i * 16 + l15) * 32 + l4 * 8];
            bF[i] = *(const f16x8*)&Bh[(wn + i * 16 + l15) * 32 + l4 * 8];
        }
#pragma unroll
        for (int i = 0; i < 4; i++)
#pragma unroll
            for (int j = 0; j < 4; j++)
                acc[i][j] = __builtin_amdgcn_mfma_f32_16x16x32_f16(aF[i], bF[j], acc[i][j], 0, 0, 0);
        __syncthreads();
    }

    float bvj[4];
#pragma unroll
    for (int j = 0; j < 4; j++) bvj[j] = bias[bn + wn + j * 16 + l15];

#pragma unroll
    for (int i = 0; i < 4; i++) {
#pragma unroll
        for (int j = 0; j < 4; j++) {
            int col = bn + wn + j * 16 + l15;
            int hh = col >> 6, dd = col & 63;
#pragma unroll
            for (int r = 0; r < 4; r++) {
                int m = bm + wm + i * 16 + l4 * 4 + r;
                float v = acc[i][j][r] + bvj[j];
                if (z == 0) {
                    qout[(size_t)m * HID + col] = v;
                } else {
                    int nbat = m >> 12, t = m & 4095;
                    _Float16 hv = (_Float16)v;
                    vout[(((size_t)(nbat * NHEAD + hh)) * TT + t) * DH + dd] = *(u16*)&hv;
                }
            }
        }
    }
}

__global__ __launch_bounds__(256) void k_gemm(
    const float* __restrict__ H, const float* __restrict__ Wk,
    const float* __restrict__ bk, const float* __restrict__ bq,
    u16* __restrict__ kout, float* __restrict__ norms)
{
    __shared__ __align__(16) u16 Ah[128 * 32];
    __shared__ __align__(16) u16 Al[128 * 32];
    __shared__ __align__(16) u16 Bh[128 * 32];
    __shared__ __align__(16) u16 Bl[128 * 32];

    const int tid  = threadIdx.x;
    const int lane = tid & 63;
    const int wid  = tid >> 6;
    const int wm = (wid >> 1) * 64;
    const int wn = (wid & 1) * 64;
    const int bm = blockIdx.x * 128;
    const int bn = blockIdx.y * 128;
    const int l15 = lane & 15, l4 = lane >> 4;

    f32x4 accM[4][4] = {};
    f32x4 accC[4][4] = {};

    for (int k0 = 0; k0 < 1024; k0 += 32) {
#pragma unroll
        for (int it = 0; it < 4; it++) {
            int c = it * 256 + tid;
            int row = c >> 3;
            int col = (c & 7) * 4;
            f32x4 a = *(const f32x4*)&H[(size_t)(bm + row) * 1024 + k0 + col];
            f32x4 b = *(const f32x4*)&Wk[(size_t)(bn + row) * 1024 + k0 + col];
            f16x4 ah, al, bh, bl;
#pragma unroll
            for (int u = 0; u < 4; u++) {
                _Float16 hh = (_Float16)a[u];
                ah[u] = hh; al[u] = (_Float16)((a[u] - (float)hh) * LO_SCALE);
                _Float16 g = (_Float16)b[u];
                bh[u] = g; bl[u] = (_Float16)((b[u] - (float)g) * LO_SCALE);
            }
            *(f16x4*)&Ah[row * 32 + col] = ah;
            *(f16x4*)&Al[row * 32 + col] = al;
            *(f16x4*)&Bh[row * 32 + col] = bh;
            *(f16x4*)&Bl[row * 32 + col] = bl;
        }
        __syncthreads();

        f16x8 aH[4], aL[4], bH[4], bL[4];
#pragma unroll
        for (int i = 0; i < 4; i++) {
            int ao = (wm + i * 16 + l15) * 32 + l4 * 8;
            int bo = (wn + i * 16 + l15) * 32 + l4 * 8;
            aH[i] = *(const f16x8*)&Ah[ao];
            aL[i] = *(const f16x8*)&Al[ao];
            bH[i] = *(const f16x8*)&Bh[bo];
            bL[i] = *(const f16x8*)&Bl[bo];
        }
#pragma unroll
        for (int i = 0; i < 4; i++)
#pragma unroll
            for (int j = 0; j < 4; j++) {
                accM[i][j] = __builtin_amdgcn_mfma_f32_16x16x32_f16(aH[i], bH[j], accM[i][j], 0, 0, 0);
                accC[i][j] = __builtin_amdgcn_mfma_f32_16x16x32_f16(aH[i], bL[j], accC[i][j], 0, 0, 0);
                accC[i][j] = __builtin_amdgcn_mfma_f32_16x16x32_f16(aL[i], bH[j], accC[i][j], 0, 0, 0);
            }
        __syncthreads();
    }

    float bkj[4], bqj[4];
#pragma unroll
    for (int j = 0; j < 4; j++) {
        bkj[j] = bk[bn + wn + j * 16 + l15];
        bqj[j] = bq[bn + wn + j * 16 + l15];
    }

#pragma unroll
    for (int i = 0; i < 4; i++) {
#pragma unroll
        for (int r = 0; r < 4; r++) {
            int m = bm + wm + i * 16 + l4 * 4 + r;
            int nbat = m >> 12, t = m & 4095;
            float sq = 0.f;
#pragma unroll
            for (int j = 0; j < 4; j++) {
                int col = bn + wn + j * 16 + l15;
                int hh = col >> 6, dd = col & 63;
                float kv = accM[i][j][r] + accC[i][j][r] * LO_INV + bkj[j];
                _Float16 hv = (_Float16)kv;
                kout[(((size_t)(nbat * NHEAD + hh)) * TT + t) * DH + dd] = *(u16*)&hv;
                float x = kv + bqj[j];
                sq = fmaf(x, x, sq);
            }
            sq += __shfl_xor(sq, 1);
            sq += __shfl_xor(sq, 2);
            sq += __shfl_xor(sq, 4);
            sq += __shfl_xor(sq, 8);
            if (l15 == 0) {
                int hh = (bn + wn) >> 6;
                norms[((size_t)(nbat * NHEAD + hh)) * TT + t] = sq;
            }
        }
    }
}

// ---------------------------------------------------------------------------
// Kernel C: norm-based top-k per 64-token chunk (stable rank by (norm, idx)).
// ---------------------------------------------------------------------------
__global__ __launch_bounds__(64) void select_topk(
    const float* __restrict__ norms_in, const float* __restrict__ mask,
    int* __restrict__ gidx, int* __restrict__ lidx)
{
    const int bid = blockIdx.x;          // nh*64 + c
    const int nh = bid >> 6, c = bid & 63;
    const int n = nh >> 4;
    const int tid = threadIdx.x;
    const int tok = c * 64 + tid;

    float nrm = norms_in[(size_t)nh * TT + tok];
    if (nrm != nrm) nrm = 0.f;                       // NaN guard
    if (mask[(size_t)n * TT + tok] != 0.f) nrm = 0.f;

    __shared__ float norms[64];
    __shared__ int flags[64];
    norms[tid] = nrm;
    __syncthreads();

    int rank = 0;
    for (int j = 0; j < 64; j++) {
        float nj = norms[j];
        rank += (nj < nrm || (nj == nrm && j < tid)) ? 1 : 0;
    }
    int istop = (rank >= 48) ? 1 : 0;
    flags[tid] = istop;
    __syncthreads();

    int pos = 0;
    for (int j = 0; j < tid; j++) pos += istop ? flags[j] : (1 - flags[j]);
    if (istop) gidx[(size_t)nh * 1024 + c * 16 + pos] = tok;
    else       lidx[(size_t)nh * 3072 + c * 48 + pos] = tok;
}

// ---------------------------------------------------------------------------
// Kernel D: BOS token — full UNSCALED attention over all keys; writes t=0.
// ---------------------------------------------------------------------------
__global__ __launch_bounds__(64) void bos_kernel(
    const u16* __restrict__ K, const u16* __restrict__ V,
    const float* __restrict__ mask, float* __restrict__ out)
{
    const int nh = blockIdx.x;
    const int n = nh >> 4, h = nh & 15;
    const int tid = threadIdx.x;
    const size_t base = (size_t)nh * TT * DH;

    float q[64];
    {
        const float* qr = out + ((size_t)n * TT) * HID + h * 64;
#pragma unroll
        for (int i = 0; i < 16; i++) {
            f32x4 v = *(const f32x4*)&qr[i * 4];
#pragma unroll
            for (int u = 0; u < 4; u++) q[i * 4 + u] = v[u];
        }
    }

    float m_ = -1e30f, l_ = 0.f, acc[64];
#pragma unroll
    for (int d = 0; d < 64; d++) acc[d] = 0.f;

    for (int kk = tid; kk < TT; kk += 64) {
        const u16* kr = K + base + (size_t)kk * DH;
        const u16* vr = V + base + (size_t)kk * DH;
        float s = 0.f;
#pragma unroll
        for (int i = 0; i < 8; i++) {
            f16x8 kv = *(const f16x8*)&kr[i * 8];
#pragma unroll
            for (int u = 0; u < 8; u++) s = fmaf(q[i * 8 + u], (float)kv[u], s);
        }
        s += mask[(size_t)n * TT + kk];   // unscaled
        float mn = fmaxf(m_, s);
        float sc = __expf(m_ - mn);
        float p  = __expf(s - mn);
        l_ = l_ * sc + p;
#pragma unroll
        for (int i = 0; i < 8; i++) {
            f16x8 vv = *(const f16x8*)&vr[i * 8];
#pragma unroll
            for (int u = 0; u < 8; u++)
                acc[i * 8 + u] = fmaf(acc[i * 8 + u], sc, p * (float)vv[u]);
        }
        m_ = mn;
    }

    __shared__ float ms[64], ls[64], accs[64][65];
    ms[tid] = m_; ls[tid] = l_;
#pragma unroll
    for (int d = 0; d < 64; d++) accs[tid][d] = acc[d];
    __syncthreads();

    float M = -1e30f;
    for (int j = 0; j < 64; j++) M = fmaxf(M, ms[j]);
    float L = 0.f;
    for (int j = 0; j < 64; j++) L += ls[j] * __expf(ms[j] - M);
    float sum = 0.f;
    for (int j = 0; j < 64; j++) sum = fmaf(accs[j][tid], __expf(ms[j] - M), sum);
    out[((size_t)n * TT) * HID + h * 64 + tid] = sum / L;
}

// ---------------------------------------------------------------------------
// Kernel E: fused selected-global + local attention + lse merge.
// 256 threads (4 waves) per (nh, 64-query chunk); lane = query; waves split
// the key stream. PV accumulation in packed fp16 (v_pk_fma_f16) folded into
// fp32 acc once per 4-key batch. Single LDS merge buffer reused G->L.
// ---------------------------------------------------------------------------
__global__ __launch_bounds__(256) void attn_kernel(
    const u16* __restrict__ K, const u16* __restrict__ V,
    const int* __restrict__ gidx, const int* __restrict__ lidx,
    const float* __restrict__ mask, float* __restrict__ out)
{
    const int bid = blockIdx.x;
    const int nh = bid >> 6, c = bid & 63;
    const int n = nh >> 4, h = nh & 15;
    const int tid = threadIdx.x;
    const int wid = tid >> 6, lane = tid & 63;
    const int t = c * 64 + lane;
    const size_t kvbase = (size_t)nh * TT * DH;
    const float* maskrow = mask + (size_t)n * TT;

    // q for this lane's query, packed to fp16 pairs (32 h2)
    h2 q2[32];
    {
        const f32x4* q4 = (const f32x4*)(out + ((size_t)n * TT + t) * HID + h * 64);
#pragma unroll
        for (int i = 0; i < 16; i++) {
            f32x4 v = q4[i];
            h2 a; a[0] = (_Float16)v[0]; a[1] = (_Float16)v[1];
            h2 b; b[0] = (_Float16)v[2]; b[1] = (_Float16)v[3];
            q2[i * 2] = a; q2[i * 2 + 1] = b;
        }
    }

    __shared__ float buf[64 * 65];                 // 16.6 KB, reused G then L
    __shared__ float msx[256], lsx[256];
    __shared__ float lseG[64], LinvG[64], lseL[64], LinvL[64];

    float m_ = -1e30f, l_ = 0.f;
    float acc[64];
#pragma unroll
    for (int d = 0; d < 64; d++) acc[d] = 0.f;

    auto batch4 = [&](int k0i, int k1i, int k2i, int k3i) {
        const uint4* k0p = (const uint4*)(K + kvbase + (size_t)k0i * DH);
        const uint4* k1p = (const uint4*)(K + kvbase + (size_t)k1i * DH);
        const uint4* k2p = (const uint4*)(K + kvbase + (size_t)k2i * DH);
        const uint4* k3p = (const uint4*)(K + kvbase + (size_t)k3i * DH);
        float s0 = 0.f, s1 = 0.f, s2 = 0.f, s3 = 0.f;
#pragma unroll
        for (int ch = 0; ch < 8; ch++) {
            U8 a, b, cc, dd; a.u = k0p[ch]; b.u = k1p[ch]; cc.u = k2p[ch]; dd.u = k3p[ch];
#pragma unroll
            for (int j = 0; j < 4; j++) {
                h2 qq = q2[ch * 4 + j];
                s0 = dot2(qq, a.h[j], s0);
                s1 = dot2(qq, b.h[j], s1);
                s2 = dot2(qq, cc.h[j], s2);
                s3 = dot2(qq, dd.h[j], s3);
            }
        }
        s0 = fmaf(s0, 0.125f, maskrow[k0i]);
        s1 = fmaf(s1, 0.125f, maskrow[k1i]);
        s2 = fmaf(s2, 0.125f, maskrow[k2i]);
        s3 = fmaf(s3, 0.125f, maskrow[k3i]);
        float bm4 = fmaxf(fmaxf(s0, s1), fmaxf(s2, s3));
        float mn = fmaxf(m_, bm4);
        float sc = __expf(m_ - mn);
        float p0 = __expf(s0 - mn), p1 = __expf(s1 - mn);
        float p2 = __expf(s2 - mn), p3 = __expf(s3 - mn);
        l_ = fmaf(l_, sc, (p0 + p1) + (p2 + p3));
        h2 ph0 = { (_Float16)p0, (_Float16)p0 };
        h2 ph1 = { (_Float16)p1, (_Float16)p1 };
        h2 ph2 = { (_Float16)p2, (_Float16)p2 };
        h2 ph3 = { (_Float16)p3, (_Float16)p3 };
        const uint4* v0p = (const uint4*)(V + kvbase + (size_t)k0i * DH);
        const uint4* v1p = (const uint4*)(V + kvbase + (size_t)k1i * DH);
        const uint4* v2p = (const uint4*)(V + kvbase + (size_t)k2i * DH);
        const uint4* v3p = (const uint4*)(V + kvbase + (size_t)k3i * DH);
#pragma unroll
        for (int ch = 0; ch < 8; ch++) {
            U8 a, b, cc, dd; a.u = v0p[ch]; b.u = v1p[ch]; cc.u = v2p[ch]; dd.u = v3p[ch];
#pragma unroll
            for (int j = 0; j < 4; j++) {
                h2 pv = a.h[j] * ph0 + b.h[j] * ph1;   // v_pk_fma_f16 chain
                pv = cc.h[j] * ph2 + pv;
                pv = dd.h[j] * ph3 + pv;
                int d0 = ch * 8 + j * 2;
                acc[d0]     = fmaf(acc[d0],     sc, (float)pv[0]);
                acc[d0 + 1] = fmaf(acc[d0 + 1], sc, (float)pv[1]);
            }
        }
        m_ = mn;
    };

    auto step1 = [&](int key, float madd) {
        const uint4* kp = (const uint4*)(K + kvbase + (size_t)key * DH);
        float s = 0.f;
#pragma unroll
        for (int ch = 0; ch < 8; ch++) {
            U8 a; a.u = kp[ch];
#pragma unroll
            for (int j = 0; j < 4; j++) s = dot2(q2[ch * 4 + j], a.h[j], s);
        }
        s = fmaf(s, 0.125f, madd);
        float mn = fmaxf(m_, s);
        float sc = __expf(m_ - mn);
        float p  = __expf(s - mn);
        l_ = fmaf(l_, sc, p);
        const uint4* vp = (const uint4*)(V + kvbase + (size_t)key * DH);
#pragma unroll
        for (int ch = 0; ch < 8; ch++) {
            U8 vv; vv.u = vp[ch];
#pragma unroll
            for (int j = 0; j < 4; j++) {
                int d0 = ch * 8 + j * 2;
                acc[d0]     = fmaf(acc[d0],     sc, p * (float)vv.h[j][0]);
                acc[d0 + 1] = fmaf(acc[d0 + 1], sc, p * (float)vv.h[j][1]);
            }
        }
        m_ = mn;
    };

    // merge 4 wave-partial states through LDS into buf; record lse, 1/L
    auto merge = [&](float* lse, float* Linv) {
        msx[wid * 64 + lane] = m_; lsx[wid * 64 + lane] = l_;
        __syncthreads();
        float M = fmaxf(fmaxf(msx[lane], msx[64 + lane]),
                        fmaxf(msx[128 + lane], msx[192 + lane]));
        float L = lsx[lane] * __expf(msx[lane] - M)
                + lsx[64 + lane] * __expf(msx[64 + lane] - M)
                + lsx[128 + lane] * __expf(msx[128 + lane] - M)
                + lsx[192 + lane] * __expf(msx[192 + lane] - M);
        float f = __expf(m_ - M);
        for (int w = 0; w < 4; w++) {
            if (wid == w) {
                if (w == 0) {
#pragma unroll
                    for (int d = 0; d < 64; d++) buf[lane * 65 + d] = acc[d] * f;
                } else {
#pragma unroll
                    for (int d = 0; d < 64; d++) buf[lane * 65 + d] += acc[d] * f;
                }
            }
            __syncthreads();
        }
        if (wid == 0) { lse[lane] = M + __logf(L); Linv[lane] = 1.f / L; }
        __syncthreads();
    };

    // ---- global (selected) pass: 3 segments x 16 keys; wave takes {wid+4j}
    const int* gp = gidx + (size_t)nh * 1024;
    for (int w3 = -1; w3 <= 1; w3++) {
        int blk = c + w3;
        if (blk < 0 || blk >= 64) continue;
        const int* seg = gp + blk * 16;
        int k0i = __builtin_amdgcn_readfirstlane(seg[wid])      & 4095;
        int k1i = __builtin_amdgcn_readfirstlane(seg[wid + 4])  & 4095;
        int k2i = __builtin_amdgcn_readfirstlane(seg[wid + 8])  & 4095;
        int k3i = __builtin_amdgcn_readfirstlane(seg[wid + 12]) & 4095;
        batch4(k0i, k1i, k2i, k3i);
    }
    merge(lseG, LinvG);

    // park ctx_g for this thread's (q, d-quarter) in registers; free buf
    float ctxg[16], lseg;
    {
        int q = tid >> 2, dq = (tid & 3) * 16;
        float lg = LinvG[q];
        lseg = lseG[q];
#pragma unroll
        for (int u = 0; u < 16; u++) ctxg[u] = buf[q * 65 + dq + u] * lg;
    }

    // ---- local pass: key 0 (wave 0) + 3 segments x 96 keys
    m_ = -1e30f; l_ = 0.f;
#pragma unroll
    for (int d = 0; d < 64; d++) acc[d] = 0.f;

    if (wid == 0) step1(0, 0.f);
    int bl = c >> 1;
    const int* lp = lidx + (size_t)nh * 3072;
    for (int w3 = -1; w3 <= 1; w3++) {
        int blk = bl + w3;
        if (blk < 0 || blk >= 32) continue;
        const int* seg = lp + blk * 96;
#pragma unroll 1
        for (int b = 0; b < 6; b++) {
            int base = wid + 16 * b;
            int k0i = __builtin_amdgcn_readfirstlane(seg[base])      & 4095;
            int k1i = __builtin_amdgcn_readfirstlane(seg[base + 4])  & 4095;
            int k2i = __builtin_amdgcn_readfirstlane(seg[base + 8])  & 4095;
            int k3i = __builtin_amdgcn_readfirstlane(seg[base + 12]) & 4095;
            batch4(k0i, k1i, k2i, k3i);
        }
    }
    merge(lseL, LinvL);

    // ---- final combine + store (thread -> quarter-row of query q)
    {
        int q = tid >> 2;
        int dq = (tid & 3) * 16;
        int tq = c * 64 + q;
        if (tq != 0) {   // t=0 row holds the bos result — keep it
            float p = 1.f / (1.f + __expf(lseg - lseL[q]));
            float ll = LinvL[q];
            size_t ob = ((size_t)n * TT + tq) * HID + h * 64 + dq;
#pragma unroll
            for (int u = 0; u < 16; u++) {
                float cl = buf[q * 65 + dq + u] * ll;
                float cg = ctxg[u];
                out[ob + u] = cg + p * (cl - cg);
            }
        }
    }
}

// ---------------------------------------------------------------------------
__global__ void ws_sentinel(float* out, int n, float val) {
    int i = blockIdx.x * 256 + threadIdx.x;
    if (i < n) out[i] = val;
}

// ---------------------------------------------------------------------------
extern "C" void kernel_launch(void* const* d_in, const int* in_sizes, int n_in,
                              void* d_out, int out_size, void* d_ws, size_t ws_size,
                              hipStream_t stream) {
    int iH = 0, iM = 1, iW[3] = {2, 4, 6}, ib[3] = {3, 5, 7};
    {
        int nw = 0, nb2 = 0, seenH = 0, seenM = 0;
        for (int i = 0; i < n_in; i++) {
            int s = in_sizes[i];
            if (s == 8388608 && !seenH) { iH = i; seenH = 1; }
            else if (s == 8192 && !seenM) { iM = i; seenM = 1; }
            else if (s == 1048576 && nw < 3) iW[nw++] = i;
            else if (s == 1024 && nb2 < 3) ib[nb2++] = i;
        }
    }
    const float* H    = (const float*)d_in[iH];
    const float* mask = (const float*)d_in[iM];
    const float* Wq = (const float*)d_in[iW[0]];
    const float* Wk = (const float*)d_in[iW[1]];
    const float* Wv = (const float*)d_in[iW[2]];
    const float* bq = (const float*)d_in[ib[0]];
    const float* bk = (const float*)d_in[ib[1]];
    const float* bv = (const float*)d_in[ib[2]];
    float* out = (float*)d_out;

    // base ws: K,V fp16 (32 MiB) + norms + indices  (= 34.6 MB, proven to fit)
    const size_t BASE_NEED = (size_t)2 * QKV_ELEMS * 2 + (size_t)NHT * TT * 4
                           + (size_t)NHT * 1024 * 4 + (size_t)NHT * 3072 * 4;
    // extended: + Hh,Hl (32 MiB) + Wq/Wv/Wk hi + Wk lo (8 MiB)
    const size_t EXT_NEED = BASE_NEED + (size_t)2 * QKV_ELEMS * 2
                          + (size_t)4 * 1048576 * 2;
    if (ws_size < BASE_NEED) {
        float val = (float)(ws_size >> 20);
        ws_sentinel<<<(out_size + 255) / 256, 256, 0, stream>>>(out, out_size, val);
        return;
    }

    u16* Kb = (u16*)d_ws;                             // [32][4096][64] fp16
    u16* Vb = Kb + (size_t)QKV_ELEMS;
    float* norms = (float*)(Vb + (size_t)QKV_ELEMS);  // [32][4096] fp32
    int* gidx = (int*)(norms + (size_t)NHT * TT);     // [32][1024]
    int* lidx = gidx + (size_t)NHT * 1024;            // [32][3072]

    if (ws_size >= EXT_NEED) {
        u16* Hh  = (u16*)(lidx + (size_t)NHT * 3072); // [8M] fp16
        u16* Hl  = Hh + (size_t)QKV_ELEMS;
        u16* Wqh = Hl + (size_t)QKV_ELEMS;            // [1M] fp16 each
        u16* Wvh = Wqh + 1048576;
        u16* Wkh = Wvh + 1048576;
        u16* Wkl = Wkh + 1048576;

        conv_split<<<8192, 256, 0, stream>>>(H, Hh, Hl, QKV_ELEMS / 4);
        conv_split<<<1024, 256, 0, stream>>>(Wk, Wkh, Wkl, 1048576 / 4);
        conv_hi<<<1024, 256, 0, stream>>>(Wq, Wqh, 1048576 / 4);
        conv_hi<<<1024, 256, 0, stream>>>(Wv, Wvh, 1048576 / 4);
        qv_gemm16<<<dim3(64, 8, 2), 256, 0, stream>>>(Hh, Wqh, Wvh, bq, bv, out, Vb);
        k_gemm16<<<dim3(64, 8), 256, 0, stream>>>(Hh, Hl, Wkh, Wkl, bk, bq, Kb, norms);
    } else {
        qv_gemm<<<dim3(64, 8, 2), 256, 0, stream>>>(H, Wq, Wv, bq, bv, out, Vb);
        k_gemm<<<dim3(64, 8), 256, 0, stream>>>(H, Wk, bk, bq, Kb, norms);
    }
    select_topk<<<NHT * 64, 64, 0, stream>>>(norms, mask, gidx, lidx);
    bos_kernel<<<NHT, 64, 0, stream>>>(Kb, Vb, mask, out);
    attn_kernel<<<NHT * 64, 256, 0, stream>>>(Kb, Vb, gidx, lidx, mask, out);
}

// Round 7
// 403.888 us; speedup vs baseline: 2.2220x; 1.4296x over previous
//
#include <hip/hip_runtime.h>
#include <hip/hip_bf16.h>

typedef unsigned short u16;
typedef __attribute__((ext_vector_type(4))) float f32x4;
typedef __attribute__((ext_vector_type(8))) _Float16 f16x8;
typedef __attribute__((ext_vector_type(4))) _Float16 f16x4;
typedef __attribute__((ext_vector_type(2))) _Float16 h2;

// dims
#define NB 2
#define TT 4096
#define HID 1024
#define NHEAD 16
#define DH 64
#define NHT (NB * NHEAD)          // 32
#define QKV_ELEMS (NHT * TT * DH) // 8388608 per tensor
#define LO_SCALE 2048.0f          // 2^11
#define LO_INV   4.8828125e-4f    // 2^-11
#define MNEG (-1.0e30f)

union U8 { uint4 u; h2 h[4]; f16x8 v; };

__device__ __forceinline__ f32x4 mf16(f16x8 a, f16x8 b, f32x4 c) {
    return __builtin_amdgcn_mfma_f32_16x16x32_f16(a, b, c, 0, 0, 0);
}

// ---------------------------------------------------------------------------
// Pre-conversion kernels: fp32 -> fp16 hi (+ 2^11*lo)
// ---------------------------------------------------------------------------
__global__ __launch_bounds__(256) void conv_split(
    const float* __restrict__ src, u16* __restrict__ hi, u16* __restrict__ lo, int n4)
{
    int i = blockIdx.x * 256 + threadIdx.x;
    if (i >= n4) return;
    f32x4 x = ((const f32x4*)src)[i];
    f16x4 h, l;
#pragma unroll
    for (int u = 0; u < 4; u++) {
        _Float16 hh = (_Float16)x[u];
        h[u] = hh;
        l[u] = (_Float16)((x[u] - (float)hh) * LO_SCALE);
    }
    ((f16x4*)hi)[i] = h;
    ((f16x4*)lo)[i] = l;
}

__global__ __launch_bounds__(256) void conv_hi(
    const float* __restrict__ src, u16* __restrict__ hi, int n4)
{
    int i = blockIdx.x * 256 + threadIdx.x;
    if (i >= n4) return;
    f32x4 x = ((const f32x4*)src)[i];
    f16x4 h;
#pragma unroll
    for (int u = 0; u < 4; u++) h[u] = (_Float16)x[u];
    ((f16x4*)hi)[i] = h;
}

// ---------------------------------------------------------------------------
// Kernel A16: Q and V projection from pre-converted fp16 inputs.
// ---------------------------------------------------------------------------
__global__ __launch_bounds__(256) void qv_gemm16(
    const u16* __restrict__ H16,
    const u16* __restrict__ Wq16, const u16* __restrict__ Wv16,
    const float* __restrict__ bq, const float* __restrict__ bv,
    float* __restrict__ qout, u16* __restrict__ vout)
{
    const int z = blockIdx.z;
    const u16* W    = (z == 0) ? Wq16 : Wv16;
    const float* bias = (z == 0) ? bq : bv;

    __shared__ __align__(16) u16 At[128 * 32];
    __shared__ __align__(16) u16 Bt[128 * 32];

    const int tid  = threadIdx.x;
    const int lane = tid & 63;
    const int wid  = tid >> 6;
    const int wm = (wid >> 1) * 64;
    const int wn = (wid & 1) * 64;
    const int bm = blockIdx.x * 128;
    const int bn = blockIdx.y * 128;
    const int l15 = lane & 15, l4 = lane >> 4;

    f32x4 acc[4][4] = {};

    for (int k0 = 0; k0 < 1024; k0 += 32) {
#pragma unroll
        for (int h2i = 0; h2i < 2; h2i++) {
            int c = h2i * 256 + tid;
            int row = c >> 2;
            int kc  = (c & 3) * 8;
            *(uint4*)&At[c * 8] = *(const uint4*)&H16[(size_t)(bm + row) * 1024 + k0 + kc];
            *(uint4*)&Bt[c * 8] = *(const uint4*)&W[(size_t)(bn + row) * 1024 + k0 + kc];
        }
        __syncthreads();

        f16x8 aF[4], bF[4];
#pragma unroll
        for (int i = 0; i < 4; i++) {
            aF[i] = *(const f16x8*)&At[(wm + i * 16 + l15) * 32 + l4 * 8];
            bF[i] = *(const f16x8*)&Bt[(wn + i * 16 + l15) * 32 + l4 * 8];
        }
#pragma unroll
        for (int i = 0; i < 4; i++)
#pragma unroll
            for (int j = 0; j < 4; j++)
                acc[i][j] = mf16(aF[i], bF[j], acc[i][j]);
        __syncthreads();
    }

    float bvj[4];
#pragma unroll
    for (int j = 0; j < 4; j++) bvj[j] = bias[bn + wn + j * 16 + l15];

#pragma unroll
    for (int i = 0; i < 4; i++) {
#pragma unroll
        for (int j = 0; j < 4; j++) {
            int col = bn + wn + j * 16 + l15;
            int hh = col >> 6, dd = col & 63;
#pragma unroll
            for (int r = 0; r < 4; r++) {
                int m = bm + wm + i * 16 + l4 * 4 + r;
                float v = acc[i][j][r] + bvj[j];
                if (z == 0) {
                    qout[(size_t)m * HID + col] = v;
                } else {
                    int nbat = m >> 12, t = m & 4095;
                    _Float16 hv = (_Float16)v;
                    vout[(((size_t)(nbat * NHEAD + hh)) * TT + t) * DH + dd] = *(u16*)&hv;
                }
            }
        }
    }
}

// ---------------------------------------------------------------------------
// Kernel B16: K projection, 2-term fp16 split (hi + 2^11*lo), 3 MFMAs.
// ---------------------------------------------------------------------------
__global__ __launch_bounds__(256) void k_gemm16(
    const u16* __restrict__ Hh, const u16* __restrict__ Hl,
    const u16* __restrict__ Wkh, const u16* __restrict__ Wkl,
    const float* __restrict__ bk, const float* __restrict__ bq,
    u16* __restrict__ kout, float* __restrict__ norms)
{
    __shared__ __align__(16) u16 Ah[128 * 32];
    __shared__ __align__(16) u16 Al[128 * 32];
    __shared__ __align__(16) u16 Bh[128 * 32];
    __shared__ __align__(16) u16 Bl[128 * 32];

    const int tid  = threadIdx.x;
    const int lane = tid & 63;
    const int wid  = tid >> 6;
    const int wm = (wid >> 1) * 64;
    const int wn = (wid & 1) * 64;
    const int bm = blockIdx.x * 128;
    const int bn = blockIdx.y * 128;
    const int l15 = lane & 15, l4 = lane >> 4;

    f32x4 accM[4][4] = {};
    f32x4 accC[4][4] = {};

    for (int k0 = 0; k0 < 1024; k0 += 32) {
#pragma unroll
        for (int h2i = 0; h2i < 2; h2i++) {
            int c = h2i * 256 + tid;
            int row = c >> 2;
            int kc  = (c & 3) * 8;
            size_t ga = (size_t)(bm + row) * 1024 + k0 + kc;
            size_t gb = (size_t)(bn + row) * 1024 + k0 + kc;
            *(uint4*)&Ah[c * 8] = *(const uint4*)&Hh[ga];
            *(uint4*)&Al[c * 8] = *(const uint4*)&Hl[ga];
            *(uint4*)&Bh[c * 8] = *(const uint4*)&Wkh[gb];
            *(uint4*)&Bl[c * 8] = *(const uint4*)&Wkl[gb];
        }
        __syncthreads();

        f16x8 aH[4], aL[4], bH[4], bL[4];
#pragma unroll
        for (int i = 0; i < 4; i++) {
            int ao = (wm + i * 16 + l15) * 32 + l4 * 8;
            int bo = (wn + i * 16 + l15) * 32 + l4 * 8;
            aH[i] = *(const f16x8*)&Ah[ao];
            aL[i] = *(const f16x8*)&Al[ao];
            bH[i] = *(const f16x8*)&Bh[bo];
            bL[i] = *(const f16x8*)&Bl[bo];
        }
#pragma unroll
        for (int i = 0; i < 4; i++)
#pragma unroll
            for (int j = 0; j < 4; j++) {
                accM[i][j] = mf16(aH[i], bH[j], accM[i][j]);
                accC[i][j] = mf16(aH[i], bL[j], accC[i][j]);
                accC[i][j] = mf16(aL[i], bH[j], accC[i][j]);
            }
        __syncthreads();
    }

    float bkj[4], bqj[4];
#pragma unroll
    for (int j = 0; j < 4; j++) {
        bkj[j] = bk[bn + wn + j * 16 + l15];
        bqj[j] = bq[bn + wn + j * 16 + l15];
    }

#pragma unroll
    for (int i = 0; i < 4; i++) {
#pragma unroll
        for (int r = 0; r < 4; r++) {
            int m = bm + wm + i * 16 + l4 * 4 + r;
            int nbat = m >> 12, t = m & 4095;
            float sq = 0.f;
#pragma unroll
            for (int j = 0; j < 4; j++) {
                int col = bn + wn + j * 16 + l15;
                int hh = col >> 6, dd = col & 63;
                float kv = accM[i][j][r] + accC[i][j][r] * LO_INV + bkj[j];
                _Float16 hv = (_Float16)kv;
                kout[(((size_t)(nbat * NHEAD + hh)) * TT + t) * DH + dd] = *(u16*)&hv;
                float x = kv + bqj[j];
                sq = fmaf(x, x, sq);
            }
            sq += __shfl_xor(sq, 1);
            sq += __shfl_xor(sq, 2);
            sq += __shfl_xor(sq, 4);
            sq += __shfl_xor(sq, 8);
            if (l15 == 0) {
                int hh = (bn + wn) >> 6;
                norms[((size_t)(nbat * NHEAD + hh)) * TT + t] = sq;
            }
        }
    }
}

// ---------------------------------------------------------------------------
// FALLBACK GEMMs (fp32 staging + convert) — used if ws small.
// ---------------------------------------------------------------------------
__global__ __launch_bounds__(256) void qv_gemm(
    const float* __restrict__ H,
    const float* __restrict__ Wq, const float* __restrict__ Wv,
    const float* __restrict__ bq, const float* __restrict__ bv,
    float* __restrict__ qout, u16* __restrict__ vout)
{
    const int z = blockIdx.z;
    const float* W    = (z == 0) ? Wq : Wv;
    const float* bias = (z == 0) ? bq : bv;

    __shared__ __align__(16) u16 Ah[128 * 32];
    __shared__ __align__(16) u16 Bh[128 * 32];

    const int tid  = threadIdx.x;
    const int lane = tid & 63;
    const int wid  = tid >> 6;
    const int wm = (wid >> 1) * 64;
    const int wn = (wid & 1) * 64;
    const int bm = blockIdx.x * 128;
    const int bn = blockIdx.y * 128;
    const int l15 = lane & 15, l4 = lane >> 4;

    f32x4 acc[4][4] = {};

    for (int k0 = 0; k0 < 1024; k0 += 32) {
#pragma unroll
        for (int it = 0; it < 4; it++) {
            int c = it * 256 + tid;
            int row = c >> 3;
            int col = (c & 7) * 4;
            f32x4 a = *(const f32x4*)&H[(size_t)(bm + row) * 1024 + k0 + col];
            f32x4 b = *(const f32x4*)&W[(size_t)(bn + row) * 1024 + k0 + col];
            f16x4 ah, bh;
#pragma unroll
            for (int u = 0; u < 4; u++) { ah[u] = (_Float16)a[u]; bh[u] = (_Float16)b[u]; }
            *(f16x4*)&Ah[row * 32 + col] = ah;
            *(f16x4*)&Bh[row * 32 + col] = bh;
        }
        __syncthreads();

        f16x8 aF[4], bF[4];
#pragma unroll
        for (int i = 0; i < 4; i++) {
            aF[i] = *(const f16x8*)&Ah[(wm + i * 16 + l15) * 32 + l4 * 8];
            bF[i] = *(const f16x8*)&Bh[(wn + i * 16 + l15) * 32 + l4 * 8];
        }
#pragma unroll
        for (int i = 0; i < 4; i++)
#pragma unroll
            for (int j = 0; j < 4; j++)
                acc[i][j] = mf16(aF[i], bF[j], acc[i][j]);
        __syncthreads();
    }

    float bvj[4];
#pragma unroll
    for (int j = 0; j < 4; j++) bvj[j] = bias[bn + wn + j * 16 + l15];

#pragma unroll
    for (int i = 0; i < 4; i++) {
#pragma unroll
        for (int j = 0; j < 4; j++) {
            int col = bn + wn + j * 16 + l15;
            int hh = col >> 6, dd = col & 63;
#pragma unroll
            for (int r = 0; r < 4; r++) {
                int m = bm + wm + i * 16 + l4 * 4 + r;
                float v = acc[i][j][r] + bvj[j];
                if (z == 0) {
                    qout[(size_t)m * HID + col] = v;
                } else {
                    int nbat = m >> 12, t = m & 4095;
                    _Float16 hv = (_Float16)v;
                    vout[(((size_t)(nbat * NHEAD + hh)) * TT + t) * DH + dd] = *(u16*)&hv;
                }
            }
        }
    }
}

__global__ __launch_bounds__(256) void k_gemm(
    const float* __restrict__ H, const float* __restrict__ Wk,
    const float* __restrict__ bk, const float* __restrict__ bq,
    u16* __restrict__ kout, float* __restrict__ norms)
{
    __shared__ __align__(16) u16 Ah[128 * 32];
    __shared__ __align__(16) u16 Al[128 * 32];
    __shared__ __align__(16) u16 Bh[128 * 32];
    __shared__ __align__(16) u16 Bl[128 * 32];

    const int tid  = threadIdx.x;
    const int lane = tid & 63;
    const int wid  = tid >> 6;
    const int wm = (wid >> 1) * 64;
    const int wn = (wid & 1) * 64;
    const int bm = blockIdx.x * 128;
    const int bn = blockIdx.y * 128;
    const int l15 = lane & 15, l4 = lane >> 4;

    f32x4 accM[4][4] = {};
    f32x4 accC[4][4] = {};

    for (int k0 = 0; k0 < 1024; k0 += 32) {
#pragma unroll
        for (int it = 0; it < 4; it++) {
            int c = it * 256 + tid;
            int row = c >> 3;
            int col = (c & 7) * 4;
            f32x4 a = *(const f32x4*)&H[(size_t)(bm + row) * 1024 + k0 + col];
            f32x4 b = *(const f32x4*)&Wk[(size_t)(bn + row) * 1024 + k0 + col];
            f16x4 ah, al, bh, bl;
#pragma unroll
            for (int u = 0; u < 4; u++) {
                _Float16 hh = (_Float16)a[u];
                ah[u] = hh; al[u] = (_Float16)((a[u] - (float)hh) * LO_SCALE);
                _Float16 g = (_Float16)b[u];
                bh[u] = g; bl[u] = (_Float16)((b[u] - (float)g) * LO_SCALE);
            }
            *(f16x4*)&Ah[row * 32 + col] = ah;
            *(f16x4*)&Al[row * 32 + col] = al;
            *(f16x4*)&Bh[row * 32 + col] = bh;
            *(f16x4*)&Bl[row * 32 + col] = bl;
        }
        __syncthreads();

        f16x8 aH[4], aL[4], bH[4], bL[4];
#pragma unroll
        for (int i = 0; i < 4; i++) {
            int ao = (wm + i * 16 + l15) * 32 + l4 * 8;
            int bo = (wn + i * 16 + l15) * 32 + l4 * 8;
            aH[i] = *(const f16x8*)&Ah[ao];
            aL[i] = *(const f16x8*)&Al[ao];
            bH[i] = *(const f16x8*)&Bh[bo];
            bL[i] = *(const f16x8*)&Bl[bo];
        }
#pragma unroll
        for (int i = 0; i < 4; i++)
#pragma unroll
            for (int j = 0; j < 4; j++) {
                accM[i][j] = mf16(aH[i], bH[j], accM[i][j]);
                accC[i][j] = mf16(aH[i], bL[j], accC[i][j]);
                accC[i][j] = mf16(aL[i], bH[j], accC[i][j]);
            }
        __syncthreads();
    }

    float bkj[4], bqj[4];
#pragma unroll
    for (int j = 0; j < 4; j++) {
        bkj[j] = bk[bn + wn + j * 16 + l15];
        bqj[j] = bq[bn + wn + j * 16 + l15];
    }

#pragma unroll
    for (int i = 0; i < 4; i++) {
#pragma unroll
        for (int r = 0; r < 4; r++) {
            int m = bm + wm + i * 16 + l4 * 4 + r;
            int nbat = m >> 12, t = m & 4095;
            float sq = 0.f;
#pragma unroll
            for (int j = 0; j < 4; j++) {
                int col = bn + wn + j * 16 + l15;
                int hh = col >> 6, dd = col & 63;
                float kv = accM[i][j][r] + accC[i][j][r] * LO_INV + bkj[j];
                _Float16 hv = (_Float16)kv;
                kout[(((size_t)(nbat * NHEAD + hh)) * TT + t) * DH + dd] = *(u16*)&hv;
                float x = kv + bqj[j];
                sq = fmaf(x, x, sq);
            }
            sq += __shfl_xor(sq, 1);
            sq += __shfl_xor(sq, 2);
            sq += __shfl_xor(sq, 4);
            sq += __shfl_xor(sq, 8);
            if (l15 == 0) {
                int hh = (bn + wn) >> 6;
                norms[((size_t)(nbat * NHEAD + hh)) * TT + t] = sq;
            }
        }
    }
}

// ---------------------------------------------------------------------------
// Kernel C: norm-based top-k per 64-token chunk.
// ---------------------------------------------------------------------------
__global__ __launch_bounds__(64) void select_topk(
    const float* __restrict__ norms_in, const float* __restrict__ mask,
    int* __restrict__ gidx, int* __restrict__ lidx)
{
    const int bid = blockIdx.x;
    const int nh = bid >> 6, c = bid & 63;
    const int n = nh >> 4;
    const int tid = threadIdx.x;
    const int tok = c * 64 + tid;

    float nrm = norms_in[(size_t)nh * TT + tok];
    if (nrm != nrm) nrm = 0.f;
    if (mask[(size_t)n * TT + tok] != 0.f) nrm = 0.f;

    __shared__ float norms[64];
    __shared__ int flags[64];
    norms[tid] = nrm;
    __syncthreads();

    int rank = 0;
    for (int j = 0; j < 64; j++) {
        float nj = norms[j];
        rank += (nj < nrm || (nj == nrm && j < tid)) ? 1 : 0;
    }
    int istop = (rank >= 48) ? 1 : 0;
    flags[tid] = istop;
    __syncthreads();

    int pos = 0;
    for (int j = 0; j < tid; j++) pos += istop ? flags[j] : (1 - flags[j]);
    if (istop) gidx[(size_t)nh * 1024 + c * 16 + pos] = tok;
    else       lidx[(size_t)nh * 3072 + c * 48 + pos] = tok;
}

// ---------------------------------------------------------------------------
// Kernel D: BOS token — full UNSCALED attention over all keys; writes t=0.
// ---------------------------------------------------------------------------
__global__ __launch_bounds__(64) void bos_kernel(
    const u16* __restrict__ K, const u16* __restrict__ V,
    const float* __restrict__ mask, float* __restrict__ out)
{
    const int nh = blockIdx.x;
    const int n = nh >> 4, h = nh & 15;
    const int tid = threadIdx.x;
    const size_t base = (size_t)nh * TT * DH;

    float q[64];
    {
        const float* qr = out + ((size_t)n * TT) * HID + h * 64;
#pragma unroll
        for (int i = 0; i < 16; i++) {
            f32x4 v = *(const f32x4*)&qr[i * 4];
#pragma unroll
            for (int u = 0; u < 4; u++) q[i * 4 + u] = v[u];
        }
    }

    float m_ = -1e30f, l_ = 0.f, acc[64];
#pragma unroll
    for (int d = 0; d < 64; d++) acc[d] = 0.f;

    for (int kk = tid; kk < TT; kk += 64) {
        const u16* kr = K + base + (size_t)kk * DH;
        const u16* vr = V + base + (size_t)kk * DH;
        float s = 0.f;
#pragma unroll
        for (int i = 0; i < 8; i++) {
            f16x8 kv = *(const f16x8*)&kr[i * 8];
#pragma unroll
            for (int u = 0; u < 8; u++) s = fmaf(q[i * 8 + u], (float)kv[u], s);
        }
        s += mask[(size_t)n * TT + kk];
        float mn = fmaxf(m_, s);
        float sc = __expf(m_ - mn);
        float p  = __expf(s - mn);
        l_ = l_ * sc + p;
#pragma unroll
        for (int i = 0; i < 8; i++) {
            f16x8 vv = *(const f16x8*)&vr[i * 8];
#pragma unroll
            for (int u = 0; u < 8; u++)
                acc[i * 8 + u] = fmaf(acc[i * 8 + u], sc, p * (float)vv[u]);
        }
        m_ = mn;
    }

    __shared__ float ms[64], ls[64], accs[64][65];
    ms[tid] = m_; ls[tid] = l_;
#pragma unroll
    for (int d = 0; d < 64; d++) accs[tid][d] = acc[d];
    __syncthreads();

    float M = -1e30f;
    for (int j = 0; j < 64; j++) M = fmaxf(M, ms[j]);
    float L = 0.f;
    for (int j = 0; j < 64; j++) L += ls[j] * __expf(ms[j] - M);
    float sum = 0.f;
    for (int j = 0; j < 64; j++) sum = fmaf(accs[j][tid], __expf(ms[j] - M), sum);
    out[((size_t)n * TT) * HID + h * 64 + tid] = sum / L;
}

// ---------------------------------------------------------------------------
// Kernel E (MFMA flash-style): fused selected-global + local attention.
// Block = 256 thr (4 waves) per (nh, 64-q chunk); wave = 16-query band.
// Gathered K/V staged in LDS; S = Q·K^T and O = P·V via mfma 16x16x32 f16;
// softmax on C-layout rows via 16-lane shfl butterflies; P via LDS round-trip.
// Invalid windows / pad keys get mask -1e30 -> p = 0 exactly (branch-free).
// Pass merge entirely in registers.
// ---------------------------------------------------------------------------
__global__ __launch_bounds__(256) void attn_kernel(
    const u16* __restrict__ K, const u16* __restrict__ V,
    const int* __restrict__ gidx, const int* __restrict__ lidx,
    const float* __restrict__ mask, float* __restrict__ out)
{
    const int bid = blockIdx.x;
    const int nh = bid >> 6, c = bid & 63;
    const int n = nh >> 4, h = nh & 15;
    const int tid = threadIdx.x;
    const int wid = tid >> 6, lane = tid & 63;
    const int l15 = lane & 15, quad = lane >> 4;
    const size_t kvbase = (size_t)nh * TT * DH;
    const float* maskrow = mask + (size_t)n * TT;

    __shared__ __align__(16) u16 Ks[96 * 72];   // gathered K rows (+pad 8)
    __shared__ __align__(16) u16 Vs[96 * 72];   // gathered V rows
    __shared__ __align__(16) u16 Ps[64 * 104];  // P matrix (A-layout source)
    __shared__ float Ms[96];                    // per-key mask add

    // Q A-frags for this wave's 16-query band: A[m=l15][k=quad*8+j]
    f16x8 aQ[2];
    {
        const float* qrow = out + ((size_t)n * TT + c * 64 + wid * 16 + l15) * HID + h * 64;
#pragma unroll
        for (int kb = 0; kb < 2; kb++) {
            f32x4 x0 = *(const f32x4*)&qrow[kb * 32 + quad * 8];
            f32x4 x1 = *(const f32x4*)&qrow[kb * 32 + quad * 8 + 4];
            f16x8 a;
#pragma unroll
            for (int u = 0; u < 4; u++) { a[u] = (_Float16)x0[u]; a[u + 4] = (_Float16)x1[u]; }
            aQ[kb] = a;
        }
    }

    // online-softmax state, C-layout: reg r <-> query band*16+quad*4+r,
    // O[j] <-> d = j*16 + l15
    float m4[4], l4[4];
    f32x4 O[4];
#pragma unroll
    for (int r = 0; r < 4; r++) { m4[r] = MNEG; l4[r] = 0.f; }
#pragma unroll
    for (int j = 0; j < 4; j++) O[j] = (f32x4){0.f, 0.f, 0.f, 0.f};

    // S over NT staged key-tiles + softmax + P write + PV over NK32 k-blocks
    auto pass_tiles = [&](int NT, int NK32) {
        f32x4 s[6];
        for (int kt = 0; kt < NT; kt++) {
            f16x8 b0 = *(const f16x8*)&Ks[(kt * 16 + l15) * 72 + quad * 8];
            f16x8 b1 = *(const f16x8*)&Ks[(kt * 16 + l15) * 72 + 32 + quad * 8];
            f32x4 a = {};
            a = mf16(aQ[0], b0, a);
            a = mf16(aQ[1], b1, a);
            float mv = Ms[kt * 16 + l15];
#pragma unroll
            for (int r = 0; r < 4; r++) a[r] = fmaf(a[r], 0.125f, mv);
            s[kt] = a;
        }
        float rmax[4];
#pragma unroll
        for (int r = 0; r < 4; r++) rmax[r] = s[0][r];
        for (int kt = 1; kt < NT; kt++)
#pragma unroll
            for (int r = 0; r < 4; r++) rmax[r] = fmaxf(rmax[r], s[kt][r]);
#pragma unroll
        for (int msk = 1; msk <= 8; msk <<= 1)
#pragma unroll
            for (int r = 0; r < 4; r++) rmax[r] = fmaxf(rmax[r], __shfl_xor(rmax[r], msk));
        float sc[4], rsum[4] = {0.f, 0.f, 0.f, 0.f};
#pragma unroll
        for (int r = 0; r < 4; r++) {
            float mn = fmaxf(m4[r], rmax[r]);
            sc[r] = __expf(m4[r] - mn);
            m4[r] = mn;
        }
        for (int kt = 0; kt < NT; kt++) {
#pragma unroll
            for (int r = 0; r < 4; r++) {
                float p = __expf(s[kt][r] - m4[r]);
                s[kt][r] = p;
                rsum[r] += p;
            }
        }
#pragma unroll
        for (int msk = 1; msk <= 8; msk <<= 1)
#pragma unroll
            for (int r = 0; r < 4; r++) rsum[r] += __shfl_xor(rsum[r], msk);
#pragma unroll
        for (int r = 0; r < 4; r++) l4[r] = fmaf(l4[r], sc[r], rsum[r]);
#pragma unroll
        for (int j = 0; j < 4; j++)
#pragma unroll
            for (int r = 0; r < 4; r++) O[j][r] *= sc[r];
        // write P (own band rows only)
        for (int kt = 0; kt < NT; kt++) {
#pragma unroll
            for (int r = 0; r < 4; r++) {
                _Float16 ph = (_Float16)s[kt][r];
                Ps[(wid * 16 + quad * 4 + r) * 104 + kt * 16 + l15] = *(u16*)&ph;
            }
        }
        __syncthreads();
        // PV
        for (int kt2 = 0; kt2 < NK32; kt2++) {
            f16x8 aP = *(const f16x8*)&Ps[(wid * 16 + l15) * 104 + kt2 * 32 + quad * 8];
#pragma unroll
            for (int j = 0; j < 4; j++) {
                f16x8 bV;
#pragma unroll
                for (int jj = 0; jj < 8; jj++) {
                    u16 raw = Vs[(kt2 * 32 + quad * 8 + jj) * 72 + j * 16 + l15];
                    bV[jj] = *(_Float16*)&raw;
                }
                O[j] = mf16(aP, bV, O[j]);
            }
        }
        __syncthreads();
    };

    // ================= GLOBAL (selected) pass: 4 tiles (48 + 16 pad) ======
#pragma unroll 1
    for (int it = 0; it < 2; it++) {
        int slot = it * 256 + tid;          // 512 slots: 64 rows x 8 chunks
        int kk = slot >> 3, ch = slot & 7;
        int tile = kk >> 4;
        int blkw = c - 1 + tile;
        bool valid = (tile < 3) && (blkw >= 0) && (blkw < 64);
        int key = valid ? (gidx[(size_t)nh * 1024 + blkw * 16 + (kk & 15)] & 4095) : 0;
        *(uint4*)&Ks[kk * 72 + ch * 8] = ((const uint4*)(K + kvbase + (size_t)key * DH))[ch];
        *(uint4*)&Vs[kk * 72 + ch * 8] = ((const uint4*)(V + kvbase + (size_t)key * DH))[ch];
        if (ch == 0) Ms[kk] = valid ? maskrow[key] : MNEG;
    }
    __syncthreads();
    pass_tiles(4, 2);

    // save global-pass state; reset for local pass
    float mG[4], lG[4];
    f32x4 OG[4];
#pragma unroll
    for (int r = 0; r < 4; r++) { mG[r] = m4[r]; lG[r] = l4[r]; m4[r] = MNEG; l4[r] = 0.f; }
#pragma unroll
    for (int j = 0; j < 4; j++) { OG[j] = O[j]; O[j] = (f32x4){0.f, 0.f, 0.f, 0.f}; }

    // ================= LOCAL pass: key0 mini-tile + 3 x 96-key segments ===
    {
        // mini: keys 0..31, only key 0 real (others masked / p = 0)
        const u16* K0 = K + kvbase;
        f16x8 b0 = *(const f16x8*)&K0[quad * 8];
        f16x8 b1 = *(const f16x8*)&K0[32 + quad * 8];
        f32x4 a = {};
        a = mf16(aQ[0], b0, a);
        a = mf16(aQ[1], b1, a);
        float mv = (l15 == 0) ? 0.f : MNEG;
        float rmax[4], sc[4], rsum[4] = {0.f, 0.f, 0.f, 0.f};
#pragma unroll
        for (int r = 0; r < 4; r++) {
            a[r] = fmaf(a[r], 0.125f, mv);
            rmax[r] = a[r];
        }
#pragma unroll
        for (int msk = 1; msk <= 8; msk <<= 1)
#pragma unroll
            for (int r = 0; r < 4; r++) rmax[r] = fmaxf(rmax[r], __shfl_xor(rmax[r], msk));
#pragma unroll
        for (int r = 0; r < 4; r++) {
            float mn = fmaxf(m4[r], rmax[r]);
            sc[r] = __expf(m4[r] - mn);
            m4[r] = mn;
            float p = __expf(a[r] - mn);
            a[r] = p;
            rsum[r] = p;
        }
#pragma unroll
        for (int msk = 1; msk <= 8; msk <<= 1)
#pragma unroll
            for (int r = 0; r < 4; r++) rsum[r] += __shfl_xor(rsum[r], msk);
#pragma unroll
        for (int r = 0; r < 4; r++) l4[r] = fmaf(l4[r], sc[r], rsum[r]);
#pragma unroll
        for (int j = 0; j < 4; j++)
#pragma unroll
            for (int r = 0; r < 4; r++) O[j][r] *= sc[r];
#pragma unroll
        for (int r = 0; r < 4; r++) {
            _Float16 ph = (_Float16)a[r];
            int prow = (wid * 16 + quad * 4 + r) * 104;
            Ps[prow + l15] = *(u16*)&ph;
            _Float16 z = (_Float16)0.f;
            Ps[prow + 16 + l15] = *(u16*)&z;
        }
        __syncthreads();
        f16x8 aP = *(const f16x8*)&Ps[(wid * 16 + l15) * 104 + quad * 8];
        const u16* V0 = V + kvbase;
#pragma unroll
        for (int j = 0; j < 4; j++) {
            u16 raw = V0[j * 16 + l15];
            _Float16 v0 = *(_Float16*)&raw;
            f16x8 bV;
#pragma unroll
            for (int u = 0; u < 8; u++) bV[u] = v0;
            O[j] = mf16(aP, bV, O[j]);
        }
        __syncthreads();
    }

    const int bl = c >> 1;
#pragma unroll 1
    for (int segi = 0; segi < 3; segi++) {
        int blkw = bl - 1 + segi;
        bool valid = (blkw >= 0) && (blkw < 32);
#pragma unroll 1
        for (int it = 0; it < 3; it++) {
            int slot = it * 256 + tid;      // 768 slots: 96 rows x 8 chunks
            int kk = slot >> 3, ch = slot & 7;
            int key = valid ? (lidx[(size_t)nh * 3072 + blkw * 96 + kk] & 4095) : 0;
            *(uint4*)&Ks[kk * 72 + ch * 8] = ((const uint4*)(K + kvbase + (size_t)key * DH))[ch];
            *(uint4*)&Vs[kk * 72 + ch * 8] = ((const uint4*)(V + kvbase + (size_t)key * DH))[ch];
            if (ch == 0) Ms[kk] = valid ? maskrow[key] : MNEG;
        }
        __syncthreads();
        pass_tiles(6, 3);
    }

    // ================= merge (registers only) + store ====================
#pragma unroll
    for (int r = 0; r < 4; r++) {
        int tq = c * 64 + wid * 16 + quad * 4 + r;
        if (tq == 0) continue;   // bos result stays
        float lseg = mG[r] + __logf(lG[r]);
        float lsel = m4[r] + __logf(l4[r]);
        float p = 1.f / (1.f + __expf(lseg - lsel));
        float ig = 1.f / lG[r], il = 1.f / l4[r];
        size_t ob = ((size_t)n * TT + tq) * HID + h * 64;
#pragma unroll
        for (int j = 0; j < 4; j++) {
            float cg = OG[j][r] * ig;
            float cl = O[j][r] * il;
            out[ob + j * 16 + l15] = cg + p * (cl - cg);
        }
    }
}

// ---------------------------------------------------------------------------
__global__ void ws_sentinel(float* out, int n, float val) {
    int i = blockIdx.x * 256 + threadIdx.x;
    if (i < n) out[i] = val;
}

// ---------------------------------------------------------------------------
extern "C" void kernel_launch(void* const* d_in, const int* in_sizes, int n_in,
                              void* d_out, int out_size, void* d_ws, size_t ws_size,
                              hipStream_t stream) {
    int iH = 0, iM = 1, iW[3] = {2, 4, 6}, ib[3] = {3, 5, 7};
    {
        int nw = 0, nb2 = 0, seenH = 0, seenM = 0;
        for (int i = 0; i < n_in; i++) {
            int s = in_sizes[i];
            if (s == 8388608 && !seenH) { iH = i; seenH = 1; }
            else if (s == 8192 && !seenM) { iM = i; seenM = 1; }
            else if (s == 1048576 && nw < 3) iW[nw++] = i;
            else if (s == 1024 && nb2 < 3) ib[nb2++] = i;
        }
    }
    const float* H    = (const float*)d_in[iH];
    const float* mask = (const float*)d_in[iM];
    const float* Wq = (const float*)d_in[iW[0]];
    const float* Wk = (const float*)d_in[iW[1]];
    const float* Wv = (const float*)d_in[iW[2]];
    const float* bq = (const float*)d_in[ib[0]];
    const float* bk = (const float*)d_in[ib[1]];
    const float* bv = (const float*)d_in[ib[2]];
    float* out = (float*)d_out;

    const size_t BASE_NEED = (size_t)2 * QKV_ELEMS * 2 + (size_t)NHT * TT * 4
                           + (size_t)NHT * 1024 * 4 + (size_t)NHT * 3072 * 4;
    const size_t EXT_NEED = BASE_NEED + (size_t)2 * QKV_ELEMS * 2
                          + (size_t)4 * 1048576 * 2;
    if (ws_size < BASE_NEED) {
        float val = (float)(ws_size >> 20);
        ws_sentinel<<<(out_size + 255) / 256, 256, 0, stream>>>(out, out_size, val);
        return;
    }

    u16* Kb = (u16*)d_ws;                             // [32][4096][64] fp16
    u16* Vb = Kb + (size_t)QKV_ELEMS;
    float* norms = (float*)(Vb + (size_t)QKV_ELEMS);  // [32][4096] fp32
    int* gidx = (int*)(norms + (size_t)NHT * TT);     // [32][1024]
    int* lidx = gidx + (size_t)NHT * 1024;            // [32][3072]

    if (ws_size >= EXT_NEED) {
        u16* Hh  = (u16*)(lidx + (size_t)NHT * 3072);
        u16* Hl  = Hh + (size_t)QKV_ELEMS;
        u16* Wqh = Hl + (size_t)QKV_ELEMS;
        u16* Wvh = Wqh + 1048576;
        u16* Wkh = Wvh + 1048576;
        u16* Wkl = Wkh + 1048576;

        conv_split<<<8192, 256, 0, stream>>>(H, Hh, Hl, QKV_ELEMS / 4);
        conv_split<<<1024, 256, 0, stream>>>(Wk, Wkh, Wkl, 1048576 / 4);
        conv_hi<<<1024, 256, 0, stream>>>(Wq, Wqh, 1048576 / 4);
        conv_hi<<<1024, 256, 0, stream>>>(Wv, Wvh, 1048576 / 4);
        qv_gemm16<<<dim3(64, 8, 2), 256, 0, stream>>>(Hh, Wqh, Wvh, bq, bv, out, Vb);
        k_gemm16<<<dim3(64, 8), 256, 0, stream>>>(Hh, Hl, Wkh, Wkl, bk, bq, Kb, norms);
    } else {
        qv_gemm<<<dim3(64, 8, 2), 256, 0, stream>>>(H, Wq, Wv, bq, bv, out, Vb);
        k_gemm<<<dim3(64, 8), 256, 0, stream>>>(H, Wk, bk, bq, Kb, norms);
    }
    select_topk<<<NHT * 64, 64, 0, stream>>>(norms, mask, gidx, lidx);
    bos_kernel<<<NHT, 64, 0, stream>>>(Kb, Vb, mask, out);
    attn_kernel<<<NHT * 64, 256, 0, stream>>>(Kb, Vb, gidx, lidx, mask, out);
}